// Round 9
// baseline (444.847 us; speedup 1.0000x reference)
//
#include <hip/hip_runtime.h>
#include <hip/hip_bf16.h>

#define B_ 64
#define N_ 245
#define NT_ 49
#define H_ 12
#define HD_ 64
#define C_ 768
#define C3_ 2304
#define M_ (B_*N_)         // 15680 tokens
#define MP_ 15744          // padded to 123*128
#define MB_ 123
#define KB_ 24             // 768/32 k-blocks
#define SCALE_ 0.125f
#define NPAD_ 256
#define NWG_QKV_ (18*123)  // 2214
#define NWG_PROJ_ (6*123)  // 738

typedef short short8 __attribute__((ext_vector_type(8)));
typedef float f32x4 __attribute__((ext_vector_type(4)));
typedef ushort us8 __attribute__((ext_vector_type(8)));
typedef ushort us4 __attribute__((ext_vector_type(4)));

__device__ __forceinline__ ushort f2bf(float f) {   // fp32 -> bf16 RTN
  unsigned u = __builtin_bit_cast(unsigned, f);
  u += 0x7fffu + ((u >> 16) & 1u);
  return (ushort)(u >> 16);
}
__device__ __forceinline__ float bf2f(ushort u) {
  return __builtin_bit_cast(float, ((unsigned)u) << 16);
}
// split a = hi + lo (both bf16; dropped error ~2^-16 relative)
__device__ __forceinline__ void split2(float a, ushort& hi, ushort& lo) {
  unsigned u = __builtin_bit_cast(unsigned, a);
  hi = (ushort)(u >> 16);
  float hf = __builtin_bit_cast(float, u & 0xffff0000u);
  lo = (ushort)(__builtin_bit_cast(unsigned, a - hf) >> 16);
}
// m204 bijective XCD swizzle
__device__ __forceinline__ int xcd_swz(int orig, int nwg) {
  const int q = nwg >> 3, r = nwg & 7;
  const int xcd = orig & 7, off = orig >> 3;
  return (xcd < r ? xcd*(q+1) : r*(q+1) + (xcd-r)*q) + off;
}

// ---- split one 8-elem chunk into the pre-tiled pre-swizzled hi|lo image ----
__device__ __forceinline__ void split_dev(
    const float* __restrict__ A, ushort* __restrict__ img, int rows, int K, int idx)
{
  const int ch = idx & 3;
  const int r  = (idx >> 2) & 127;
  const int t  = idx >> 9;
  const int KBl = K >> 5;
  const int kb = t % KBl, mb = t / KBl;
  const int m = mb*128 + r;
  float4 v0 = make_float4(0,0,0,0), v1 = make_float4(0,0,0,0);
  if (m < rows) {
    const float* p = A + (size_t)m*K + kb*32 + ch*8;
    v0 = *(const float4*)p; v1 = *(const float4*)(p+4);
  }
  float vals[8] = {v0.x,v0.y,v0.z,v0.w,v1.x,v1.y,v1.z,v1.w};
  us8 hv, lv;
  #pragma unroll
  for (int e = 0; e < 8; ++e) { ushort hh, ll; split2(vals[e], hh, ll); hv[e]=hh; lv[e]=ll; }
  ushort* base = img + ((size_t)t*128 + r)*64;
  const int sw = (ch ^ (r&7))*8;
  *(us8*)(base + sw)        = hv;
  *(us8*)(base + (sw ^ 32)) = lv;
}

// ---- merged prep: x/w splits + bf16 biasT gather + G GEMV ----
#define PREP_X_   5904   // 123*24*512/256
#define PREP_WQ_  864    // 18*24*512/256
#define PREP_WP_  288    // 6*24*512/256
#define PREP_BT_  2814   // ceil(12*245*245/256)
#define PREP_G_   768    // B_*H_
__global__ __launch_bounds__(256) void prep_kernel(
    const float* __restrict__ x, const float* __restrict__ qkv_w,
    const float* __restrict__ proj_w, const float* __restrict__ rpe_table,
    const int* __restrict__ rpe_index, const float* __restrict__ boxmask,
    const float* __restrict__ box_w,
    ushort* __restrict__ ximg, ushort* __restrict__ wqkvimg, ushort* __restrict__ wprojimg,
    ushort* __restrict__ biasTb, float* __restrict__ G, int rpe_m)
{
  __shared__ float bms[NT_][65];
  __shared__ float bws[H_][65];
  int id = blockIdx.x;
  const int tid = threadIdx.x;
  if (id < PREP_X_)  { split_dev(x,      ximg,     M_,  C_, id*256 + tid); return; }
  id -= PREP_X_;
  if (id < PREP_WQ_) { split_dev(qkv_w,  wqkvimg,  C3_, C_, id*256 + tid); return; }
  id -= PREP_WQ_;
  if (id < PREP_WP_) { split_dev(proj_w, wprojimg, C_,  C_, id*256 + tid); return; }
  id -= PREP_WP_;
  if (id < PREP_BT_) {
    int idx = id*256 + tid;
    if (idx < H_*N_*N_) {
      int h = idx / (N_*N_);
      int rem = idx % (N_*N_);
      int j = rem / N_, i = rem % N_;
      biasTb[((size_t)h*NPAD_ + j)*NPAD_ + i] = f2bf(rpe_table[h*rpe_m + rpe_index[i*N_ + j]]);
    }
    return;
  }
  id -= PREP_BT_;
  // G role: id = b*12 + ht
  {
    const int b = id / H_, ht = id % H_;
    for (int idx = tid; idx < NT_*64; idx += 256) {
      int j = idx >> 6, d = idx & 63;
      bms[j][d] = boxmask[((size_t)(b*NT_ + j))*C_ + ht*64 + d];
    }
    for (int idx = tid; idx < H_*64; idx += 256) {
      int h = idx >> 6, d = idx & 63;
      bws[h][d] = box_w[(size_t)h*C_ + ht*64 + d];
    }
    __syncthreads();
    for (int o = tid; o < H_*64; o += 256) {
      int h = o >> 6, j = o & 63;
      float s = 0.f;
      if (j < NT_) {
        #pragma unroll
        for (int d = 0; d < 64; ++d) s = fmaf(bws[h][d], bms[j][d], s);
      }
      G[(size_t)id*H_*64 + o] = s;
    }
  }
}

// ---- stage one 16KB tile linearly into LDS ----
__device__ __forceinline__ void stage_tile(const ushort* __restrict__ src, ushort* dst,
                                           int wid, int lane) {
  #pragma unroll
  for (int t = 0; t < 4; ++t) {
    const int o = (wid*4 + t) * 512;
    __builtin_amdgcn_global_load_lds(
      (const __attribute__((address_space(1))) unsigned int*)(src + o + lane*8),
      (__attribute__((address_space(3))) unsigned int*)(dst + o),
      16, 0, 0);
  }
}

// ---- bf16x3 GEMM (token-major A): Co = A @ B^T + bias, fp32 out (proj) ----
__global__ __launch_bounds__(256) void gemm3_kernel(
    const ushort* __restrict__ Aimg, const ushort* __restrict__ Bimg,
    const float* __restrict__ bias, float* __restrict__ Co,
    int KB, int Nn, int M)
{
  __shared__ __align__(16) ushort lds[2][16384];
  const int tid = threadIdx.x, lane = tid & 63, wid = tid >> 6;
  const int g = lane >> 4, li = lane & 15;
  const int sid = xcd_swz(blockIdx.x, NWG_PROJ_);
  const int nb = sid % 6, mb = sid / 6;
  const int wr = (wid >> 1) * 64, wc = (wid & 1) * 64;

  const ushort* Abase = Aimg + (size_t)mb * KB * 8192;
  const ushort* Bbase = Bimg + (size_t)nb * KB * 8192;

  f32x4 acc[4][4];
  #pragma unroll
  for (int i = 0; i < 4; ++i)
    #pragma unroll
    for (int j = 0; j < 4; ++j) acc[i][j] = (f32x4){0.f,0.f,0.f,0.f};

  stage_tile(Abase, &lds[0][0],    wid, lane);
  stage_tile(Bbase, &lds[0][8192], wid, lane);
  __syncthreads();

  for (int kb = 0; kb < KB; ++kb) {
    const int cur = kb & 1;
    if (kb + 1 < KB) {
      stage_tile(Abase + (size_t)(kb+1)*8192, &lds[cur^1][0],    wid, lane);
      stage_tile(Bbase + (size_t)(kb+1)*8192, &lds[cur^1][8192], wid, lane);
    }
    short8 ah[4], al[4], bh[4], bl[4];
    #pragma unroll
    for (int t = 0; t < 4; ++t) {
      const int ra = wr + t*16 + li;
      const ushort* Ar = &lds[cur][ra*64];
      const int ca = (g ^ (ra & 7)) * 8;
      ah[t] = *(const short8*)(Ar + ca);
      al[t] = *(const short8*)(Ar + (ca ^ 32));
      const int rb = wc + t*16 + li;
      const ushort* Br = &lds[cur][8192 + rb*64];
      const int cb = (g ^ (rb & 7)) * 8;
      bh[t] = *(const short8*)(Br + cb);
      bl[t] = *(const short8*)(Br + (cb ^ 32));
    }
    #pragma unroll
    for (int i = 0; i < 4; ++i)
      #pragma unroll
      for (int j = 0; j < 4; ++j) {
        acc[i][j] = __builtin_amdgcn_mfma_f32_16x16x32_bf16(ah[i], bh[j], acc[i][j], 0,0,0);
        acc[i][j] = __builtin_amdgcn_mfma_f32_16x16x32_bf16(al[i], bh[j], acc[i][j], 0,0,0);
        acc[i][j] = __builtin_amdgcn_mfma_f32_16x16x32_bf16(ah[i], bl[j], acc[i][j], 0,0,0);
      }
    __syncthreads();
  }

  #pragma unroll
  for (int i = 0; i < 4; ++i) {
    const int m0 = mb*128 + wr + i*16 + g*4;
    #pragma unroll
    for (int j = 0; j < 4; ++j) {
      const int n = nb*128 + wc + j*16 + li;
      const float bv = bias[n];
      #pragma unroll
      for (int rr = 0; rr < 4; ++rr) {
        const int m = m0 + rr;
        if (m < M) Co[(size_t)m * Nn + n] = acc[i][j][rr] + bv;
      }
    }
  }
}

// ---- bf16x3 QKV GEMM (W-major A): writes bf16 Q/K/VT images directly ----
// VT image is subtiled [dt 4][jc 8][dr 16][kk 32] per head for coalesced PV fragment reads.
__global__ __launch_bounds__(256) void gemm3_qkv_kernel(
    const ushort* __restrict__ Aimg, const ushort* __restrict__ Bimg,
    const float* __restrict__ bias,
    ushort* __restrict__ Qimg, ushort* __restrict__ Kimg, ushort* __restrict__ VTimg,
    int KB)
{
  __shared__ __align__(16) ushort lds[2][16384];
  const int tid = threadIdx.x, lane = tid & 63, wid = tid >> 6;
  const int g = lane >> 4, li = lane & 15;
  const int sid = xcd_swz(blockIdx.x, NWG_QKV_);
  const int mb = sid % 18, nb = sid / 18;   // mb: channel block (fastest), nb: token block
  const int wr = (wid >> 1) * 64, wc = (wid & 1) * 64;

  const ushort* Abase = Aimg + (size_t)mb * KB * 8192;
  const ushort* Bbase = Bimg + (size_t)nb * KB * 8192;

  f32x4 acc[4][4];
  #pragma unroll
  for (int i = 0; i < 4; ++i)
    #pragma unroll
    for (int j = 0; j < 4; ++j) acc[i][j] = (f32x4){0.f,0.f,0.f,0.f};

  stage_tile(Abase, &lds[0][0],    wid, lane);
  stage_tile(Bbase, &lds[0][8192], wid, lane);
  __syncthreads();

  for (int kb = 0; kb < KB; ++kb) {
    const int cur = kb & 1;
    if (kb + 1 < KB) {
      stage_tile(Abase + (size_t)(kb+1)*8192, &lds[cur^1][0],    wid, lane);
      stage_tile(Bbase + (size_t)(kb+1)*8192, &lds[cur^1][8192], wid, lane);
    }
    short8 ah[4], al[4], bh[4], bl[4];
    #pragma unroll
    for (int t = 0; t < 4; ++t) {
      const int ra = wr + t*16 + li;
      const ushort* Ar = &lds[cur][ra*64];
      const int ca = (g ^ (ra & 7)) * 8;
      ah[t] = *(const short8*)(Ar + ca);
      al[t] = *(const short8*)(Ar + (ca ^ 32));
      const int rb = wc + t*16 + li;
      const ushort* Br = &lds[cur][8192 + rb*64];
      const int cb = (g ^ (rb & 7)) * 8;
      bh[t] = *(const short8*)(Br + cb);
      bl[t] = *(const short8*)(Br + (cb ^ 32));
    }
    #pragma unroll
    for (int i = 0; i < 4; ++i)
      #pragma unroll
      for (int j = 0; j < 4; ++j) {
        acc[i][j] = __builtin_amdgcn_mfma_f32_16x16x32_bf16(ah[i], bh[j], acc[i][j], 0,0,0);
        acc[i][j] = __builtin_amdgcn_mfma_f32_16x16x32_bf16(al[i], bh[j], acc[i][j], 0,0,0);
        acc[i][j] = __builtin_amdgcn_mfma_f32_16x16x32_bf16(ah[i], bl[j], acc[i][j], 0,0,0);
      }
    __syncthreads();
  }

  // epilogue: quad = channels ch0..ch0+3 at one token per (j,li)
  #pragma unroll
  for (int i = 0; i < 4; ++i) {
    const int ch0 = mb*128 + wr + i*16 + g*4;
    const int part = ch0 / 768;           // 0=q 1=k 2=v (uniform within quad/tile)
    const int rem  = ch0 - part*768;
    const int h = rem >> 6, d0 = rem & 63;
    const float b0 = bias[ch0+0], b1 = bias[ch0+1], b2 = bias[ch0+2], b3 = bias[ch0+3];
    #pragma unroll
    for (int j = 0; j < 4; ++j) {
      const int tok = nb*128 + wc + j*16 + li;
      if (tok < M_) {
        const int b = tok / 245;
        const int jl = tok - b*245;
        const int bh = b*H_ + h;
        if (part == 0) {
          us4 q4 = { f2bf((acc[i][j][0] + b0)*SCALE_), f2bf((acc[i][j][1] + b1)*SCALE_),
                     f2bf((acc[i][j][2] + b2)*SCALE_), f2bf((acc[i][j][3] + b3)*SCALE_) };
          *(us4*)(Qimg + ((size_t)bh*NPAD_ + jl)*64 + d0) = q4;
        } else if (part == 1) {
          us4 k4 = { f2bf(acc[i][j][0] + b0), f2bf(acc[i][j][1] + b1),
                     f2bf(acc[i][j][2] + b2), f2bf(acc[i][j][3] + b3) };
          *(us4*)(Kimg + ((size_t)bh*NPAD_ + jl)*64 + (d0 ^ ((jl&7)<<3))) = k4;
        } else {
          // tiled VT: [dt][jc][dr][kk], subtile contiguous 512 ushorts
          const int dt = d0 >> 4, dr = d0 & 15;
          const int jc2 = jl >> 5, kk = jl & 31;
          ushort* vb = VTimg + (size_t)bh*16384 + ((dt*8 + jc2)*16 + dr)*32 + kk;
          vb[0]  = f2bf(acc[i][j][0] + b0);
          vb[32] = f2bf(acc[i][j][1] + b1);
          vb[64] = f2bf(acc[i][j][2] + b2);
          vb[96] = f2bf(acc[i][j][3] + b3);
        }
      }
    }
  }
}

// -------- template attention (MFMA) -> F_part[b,h,i,ht] = sum_j P[i,j]*G[b,ht,h,j] --------
__global__ __launch_bounds__(256) void tmpl_kernel(
    const ushort* __restrict__ Qimg, const ushort* __restrict__ Kimg,
    const float* __restrict__ G, const ushort* __restrict__ biasTb,
    float* __restrict__ F_part)
{
  __shared__ __align__(16) ushort kt_lds[64*64];   // first 64 K rows (swizzled image)
  __shared__ __align__(16) float Gs[H_*64];
  const int bx = blockIdx.x;       // b*12 + ht
  const int b = bx / H_, ht = bx % H_;
  const int tid = threadIdx.x, lane = tid & 63, wid = tid >> 6;
  const int g = lane >> 4, li = lane & 15;

  const ushort* Kb = Kimg + (size_t)bx*NPAD_*64;
  #pragma unroll
  for (int t = 0; t < 2; ++t) {
    const int o = (t*4 + wid) * 512;
    __builtin_amdgcn_global_load_lds(
      (const __attribute__((address_space(1))) unsigned int*)(Kb + o + lane*8),
      (__attribute__((address_space(3))) unsigned int*)(kt_lds + o), 16, 0, 0);
  }
  for (int idx = tid; idx < H_*64; idx += 256) Gs[idx] = G[(size_t)bx*H_*64 + idx];

  const int i = wid*16 + li;       // q-row 0..63 (template rows are 0..48)
  short8 bq[2];
  {
    const ushort* qp = Qimg + ((size_t)bx*NPAD_ + i)*64;   // Q pre-scaled
    bq[0] = *(const short8*)(qp + g*8);
    bq[1] = *(const short8*)(qp + 32 + g*8);
  }
  __syncthreads();

  f32x4 sacc[4];
  #pragma unroll
  for (int jt = 0; jt < 4; ++jt) sacc[jt] = (f32x4){0.f,0.f,0.f,0.f};
  #pragma unroll
  for (int jt = 0; jt < 4; ++jt) {
    int jr = jt*16 + li;
    #pragma unroll
    for (int kc = 0; kc < 2; ++kc) {
      short8 af = *(const short8*)(kt_lds + jr*64 + ((kc*32 + g*8) ^ ((jr&7)<<3)));
      sacc[jt] = __builtin_amdgcn_mfma_f32_16x16x32_bf16(af, bq[kc], sacc[jt], 0, 0, 0);
    }
  }

  const ushort* bT = biasTb + (size_t)ht*NPAD_*NPAD_;
  float mloc = 0.f;                 // masked zeros join the max
  #pragma unroll
  for (int jt = 0; jt < 4; ++jt)
    #pragma unroll
    for (int r = 0; r < 4; ++r) {
      int j = jt*16 + g*4 + r;
      float sv = (j < NT_) ? (sacc[jt][r] + bf2f(bT[(size_t)j*NPAD_ + i])) : -1e30f;
      sacc[jt][r] = sv;
      mloc = fmaxf(mloc, sv);
    }
  mloc = fmaxf(mloc, __shfl_xor(mloc, 16));
  mloc = fmaxf(mloc, __shfl_xor(mloc, 32));
  float ssum = 0.f;
  #pragma unroll
  for (int jt = 0; jt < 4; ++jt)
    #pragma unroll
    for (int r = 0; r < 4; ++r) {
      int j = jt*16 + g*4 + r;
      float e = (j < NT_) ? __expf(sacc[jt][r] - mloc) : 0.f;
      sacc[jt][r] = e;
      ssum += e;
    }
  ssum += __shfl_xor(ssum, 16);
  ssum += __shfl_xor(ssum, 32);
  const float inv = 1.f / (ssum + 196.f * __expf(-mloc));   // 196 masked exp(0-mx)

  float F[12];
  #pragma unroll
  for (int h = 0; h < 12; ++h) F[h] = 0.f;
  #pragma unroll
  for (int jt = 0; jt < 4; ++jt) {
    f32x4 p = sacc[jt] * inv;
    #pragma unroll
    for (int h = 0; h < 12; ++h) {
      const float4 g4 = *(const float4*)(&Gs[h*64 + jt*16 + g*4]);
      F[h] = fmaf(p[0], g4.x, fmaf(p[1], g4.y, fmaf(p[2], g4.z, fmaf(p[3], g4.w, F[h]))));
    }
  }
  #pragma unroll
  for (int h = 0; h < 12; ++h) {
    F[h] += __shfl_xor(F[h], 16);
    F[h] += __shfl_xor(F[h], 32);
  }
  if (lane < 16 && i < NT_) {
    #pragma unroll
    for (int h = 0; h < 12; ++h)
      F_part[((size_t)(b*H_ + h)*NT_ + i)*12 + ht] = F[h];
  }
}

// -------- MFMA flash attention; V read coalesced from tiled VT image --------
__global__ __launch_bounds__(256) void attn_mfma_kernel(
    const ushort* __restrict__ Qimg, const ushort* __restrict__ Kimg,
    const ushort* __restrict__ VTimg, const ushort* __restrict__ biasTb,
    const float* __restrict__ F_part, const float* __restrict__ box_b,
    ushort* __restrict__ attnimg)
{
  __shared__ __align__(16) ushort kp_lds[NPAD_*64];   // K image; then P; then O-transpose
  const int bx = blockIdx.x;
  const int bh = bx >> 2, rb = bx & 3;
  const int b = bh / H_, h = bh % H_;
  const int tid = threadIdx.x, lane = tid & 63, wid = tid >> 6;
  const int g = lane >> 4, li = lane & 15;

  const ushort* Kb = Kimg  + (size_t)bh*16384;
  const ushort* Vb = VTimg + (size_t)bh*16384;
  #pragma unroll
  for (int t = 0; t < 8; ++t) {
    const int o = (t*4 + wid) * 512;
    __builtin_amdgcn_global_load_lds(
      (const __attribute__((address_space(1))) unsigned int*)(Kb + o + lane*8),
      (__attribute__((address_space(3))) unsigned int*)(kp_lds + o), 16, 0, 0);
  }

  const int i0 = rb*64 + wid*16;
  const int ig = i0 + li;
  const int iq = (ig < N_) ? ig : (N_-1);
  short8 bq[2];
  {
    const ushort* qp = Qimg + ((size_t)bh*NPAD_ + iq)*64;   // Q pre-scaled
    bq[0] = *(const short8*)(qp + g*8);
    bq[1] = *(const short8*)(qp + 32 + g*8);
  }
  __syncthreads();

  f32x4 sacc[16];
  #pragma unroll
  for (int jt = 0; jt < 16; ++jt) sacc[jt] = (f32x4){0.f,0.f,0.f,0.f};
  __builtin_amdgcn_s_setprio(1);
  #pragma unroll
  for (int jt = 0; jt < 16; ++jt) {
    int jr = jt*16 + li;
    #pragma unroll
    for (int kc = 0; kc < 2; ++kc) {
      short8 af = *(const short8*)(kp_lds + jr*64 + ((kc*32 + g*8) ^ ((jr&7)<<3)));
      sacc[jt] = __builtin_amdgcn_mfma_f32_16x16x32_bf16(af, bq[kc], sacc[jt], 0, 0, 0);
    }
  }
  __builtin_amdgcn_s_setprio(0);
  __syncthreads();   // all waves done reading K; kp_lds becomes P

  float fac = 1.0f;
  if (ig < NT_) {
    const float* fp = F_part + ((size_t)bh*NT_ + ig)*12;
    float4 f0 = *(const float4*)fp;
    float4 f1 = *(const float4*)(fp+4);
    float4 f2 = *(const float4*)(fp+8);
    fac = box_b[h] + f0.x+f0.y+f0.z+f0.w + f1.x+f1.y+f1.z+f1.w + f2.x+f2.y+f2.z+f2.w;
  }
  const ushort* bT = biasTb + (size_t)h*NPAD_*NPAD_;
  float mloc = -1e30f;
  #pragma unroll
  for (int jt = 0; jt < 16; ++jt) {
    #pragma unroll
    for (int r = 0; r < 4; ++r) {
      int j = jt*16 + g*4 + r;
      float sv = sacc[jt][r] + bf2f(bT[(size_t)j*NPAD_ + i0 + li]);
      if (ig < NT_ && j >= NT_) sv *= fac;
      if (j >= N_) sv = -1e30f;
      sacc[jt][r] = sv;
      mloc = fmaxf(mloc, sv);
    }
  }
  mloc = fmaxf(mloc, __shfl_xor(mloc, 16));
  mloc = fmaxf(mloc, __shfl_xor(mloc, 32));
  float ssum = 0.f;
  #pragma unroll
  for (int jt = 0; jt < 16; ++jt) {
    #pragma unroll
    for (int r = 0; r < 4; ++r) {
      float e = __expf(sacc[jt][r] - mloc);
      sacc[jt][r] = e;
      ssum += e;
    }
  }
  ssum += __shfl_xor(ssum, 16);
  ssum += __shfl_xor(ssum, 32);
  const float inv = 1.0f / ssum;

  ushort* pbase = kp_lds + wid*4096 + li*256;
  const int swz = (li & 7) << 3;
  #pragma unroll
  for (int jt = 0; jt < 16; ++jt) {
    unsigned w0 = (unsigned)f2bf(sacc[jt][0]*inv) | ((unsigned)f2bf(sacc[jt][1]*inv) << 16);
    unsigned w1 = (unsigned)f2bf(sacc[jt][2]*inv) | ((unsigned)f2bf(sacc[jt][3]*inv) << 16);
    *(uint2*)(pbase + ((jt*16 + g*4) ^ swz)) = make_uint2(w0, w1);
  }

  f32x4 oacc[4];
  #pragma unroll
  for (int dt = 0; dt < 4; ++dt) oacc[dt] = (f32x4){0.f,0.f,0.f,0.f};
  __builtin_amdgcn_s_setprio(1);
  #pragma unroll
  for (int jc = 0; jc < 8; ++jc) {
    short8 pf = *(const short8*)(pbase + ((jc*32 + g*8) ^ swz));
    #pragma unroll
    for (int dt = 0; dt < 4; ++dt) {
      // tiled VT read: contiguous 1KB per wave fragment
      short8 vf = *(const short8*)(Vb + (dt*8 + jc)*512 + li*32 + g*8);
      oacc[dt] = __builtin_amdgcn_mfma_f32_16x16x32_bf16(vf, pf, oacc[dt], 0, 0, 0);
    }
  }
  __builtin_amdgcn_s_setprio(0);

  // ---- per-wave LDS transpose in own 8KB region (no barrier needed) ----
  float* tb = (float*)(kp_lds + wid*4096);
  #pragma unroll
  for (int dt = 0; dt < 4; ++dt)
    #pragma unroll
    for (int rr = 0; rr < 4; ++rr)
      tb[(dt*16 + g*4 + rr)*19 + li] = oacc[dt][rr];

  const int rtok = lane >> 2, cg = lane & 3;
  const int tokl = i0 + rtok;
  if (tokl < N_) {
    const int m = b*N_ + tokl;
    const int mbm = m >> 7, rr_ = m & 127, rx = rr_ & 7;
    const int kbb = h*2 + (cg >> 1);
    ushort* baseimg = attnimg + (((size_t)(mbm*KB_ + kbb))*128 + rr_)*64;
    #pragma unroll
    for (int half = 0; half < 2; ++half) {
      us8 hv, lv;
      #pragma unroll
      for (int e = 0; e < 8; ++e) {
        float v = tb[(cg*16 + half*8 + e)*19 + rtok];
        ushort hh, ll; split2(v, hh, ll);
        hv[e] = hh; lv[e] = ll;
      }
      const int c0 = (cg & 1)*2 + half;
      *(us8*)(baseimg + ((c0 ^ rx) * 8))        = hv;
      *(us8*)(baseimg + (((c0 ^ 4) ^ rx) * 8))  = lv;
    }
  }
}

extern "C" void kernel_launch(void* const* d_in, const int* in_sizes, int n_in,
                              void* d_out, int out_size, void* d_ws, size_t ws_size,
                              hipStream_t stream)
{
  const float* x         = (const float*)d_in[0];
  const float* boxmask   = (const float*)d_in[1];
  const float* qkv_w     = (const float*)d_in[2];
  const float* qkv_b     = (const float*)d_in[3];
  const float* proj_w    = (const float*)d_in[4];
  const float* proj_b    = (const float*)d_in[5];
  const float* box_w     = (const float*)d_in[6];
  const float* box_b     = (const float*)d_in[7];
  const float* rpe_table = (const float*)d_in[8];
  const int*   rpe_index = (const int*)d_in[9];
  const int rpe_m = in_sizes[8] / H_;   // 1698

  float* ws      = (float*)d_ws;
  float* G       = ws;                                   // 589,824 f
  float* F_part  = G + (size_t)B_*H_*H_*64;              // 451,584 f
  ushort* biasTb = (ushort*)(F_part + (size_t)B_*H_*NT_*12);  // 786,432 us
  ushort* ximg    = biasTb   + (size_t)H_*NPAD_*NPAD_;
  ushort* wqkvimg  = ximg     + (size_t)MP_*C_*2;        // 24,182,784 us
  ushort* wprojimg = wqkvimg  + (size_t)C3_*C_*2;        // 3,538,944 us
  ushort* Qimg     = wprojimg + (size_t)C_*C_*2;         // 1,179,648 us
  ushort* Kimg     = Qimg     + (size_t)B_*H_*NPAD_*64;  // 12,582,912 us each
  ushort* VTimg    = Kimg     + (size_t)B_*H_*NPAD_*64;
  ushort* attnimg  = ximg;   // alias: x image dead after QKV GEMM
  float* out     = (float*)d_out;

  // 0) merged prep: splits + bf16 biasT + G
  prep_kernel<<<PREP_X_+PREP_WQ_+PREP_WP_+PREP_BT_+PREP_G_, 256, 0, stream>>>(
      x, qkv_w, proj_w, rpe_table, rpe_index, boxmask, box_w,
      ximg, wqkvimg, wprojimg, biasTb, G, rpe_m);
  // 1) QKV projection -> bf16 Q/K/VT images (XCD-swizzled 1D grid)
  gemm3_qkv_kernel<<<NWG_QKV_, 256, 0, stream>>>(wqkvimg, ximg, qkv_b, Qimg, Kimg, VTimg, KB_);
  // 2) template attention (MFMA) -> F_part
  tmpl_kernel<<<B_*H_, 256, 0, stream>>>(Qimg, Kimg, G, biasTb, F_part);
  // 3) MFMA attention -> attn image
  attn_mfma_kernel<<<B_*H_*4, 256, 0, stream>>>(Qimg, Kimg, VTimg, biasTb, F_part, box_b, attnimg);
  // 4) output projection (bf16x3 MFMA, fp32 out, XCD-swizzled)
  gemm3_kernel<<<NWG_PROJ_, 256, 0, stream>>>(attnimg, wprojimg, proj_b, out, KB_, C_, M_);
}

// Round 11
// 444.729 us; speedup vs baseline: 1.0003x; 1.0003x over previous
//
#include <hip/hip_runtime.h>
#include <hip/hip_bf16.h>

#define B_ 64
#define N_ 245
#define NT_ 49
#define H_ 12
#define HD_ 64
#define C_ 768
#define C3_ 2304
#define M_ (B_*N_)         // 15680 tokens
#define MP_ 15744          // padded to 123*128
#define MB_ 123
#define KB_ 24             // 768/32 k-blocks
#define SCALE_ 0.125f
#define NPAD_ 256
#define NWG_QKV_ (18*123)  // 2214
#define NWG_PROJ_ (6*123)  // 738

typedef short short8 __attribute__((ext_vector_type(8)));
typedef float f32x4 __attribute__((ext_vector_type(4)));
typedef ushort us8 __attribute__((ext_vector_type(8)));
typedef ushort us4 __attribute__((ext_vector_type(4)));

__device__ __forceinline__ ushort f2bf(float f) {   // fp32 -> bf16 RTN
  unsigned u = __builtin_bit_cast(unsigned, f);
  u += 0x7fffu + ((u >> 16) & 1u);
  return (ushort)(u >> 16);
}
__device__ __forceinline__ float bf2f(ushort u) {
  return __builtin_bit_cast(float, ((unsigned)u) << 16);
}
// split a = hi + lo (both bf16; dropped error ~2^-16 relative)
__device__ __forceinline__ void split2(float a, ushort& hi, ushort& lo) {
  unsigned u = __builtin_bit_cast(unsigned, a);
  hi = (ushort)(u >> 16);
  float hf = __builtin_bit_cast(float, u & 0xffff0000u);
  lo = (ushort)(__builtin_bit_cast(unsigned, a - hf) >> 16);
}
// m204 bijective XCD swizzle
__device__ __forceinline__ int xcd_swz(int orig, int nwg) {
  const int q = nwg >> 3, r = nwg & 7;
  const int xcd = orig & 7, off = orig >> 3;
  return (xcd < r ? xcd*(q+1) : r*(q+1) + (xcd-r)*q) + off;
}

// ---- split one 8-elem chunk into the pre-tiled pre-swizzled hi|lo image ----
__device__ __forceinline__ void split_dev(
    const float* __restrict__ A, ushort* __restrict__ img, int rows, int K, int idx)
{
  const int ch = idx & 3;
  const int r  = (idx >> 2) & 127;
  const int t  = idx >> 9;
  const int KBl = K >> 5;
  const int kb = t % KBl, mb = t / KBl;
  const int m = mb*128 + r;
  float4 v0 = make_float4(0,0,0,0), v1 = make_float4(0,0,0,0);
  if (m < rows) {
    const float* p = A + (size_t)m*K + kb*32 + ch*8;
    v0 = *(const float4*)p; v1 = *(const float4*)(p+4);
  }
  float vals[8] = {v0.x,v0.y,v0.z,v0.w,v1.x,v1.y,v1.z,v1.w};
  us8 hv, lv;
  #pragma unroll
  for (int e = 0; e < 8; ++e) { ushort hh, ll; split2(vals[e], hh, ll); hv[e]=hh; lv[e]=ll; }
  ushort* base = img + ((size_t)t*128 + r)*64;
  const int sw = (ch ^ (r&7))*8;
  *(us8*)(base + sw)        = hv;
  *(us8*)(base + (sw ^ 32)) = lv;
}

// ---- merged prep: x/w splits + bf16 biasT gather (i-major) + G GEMV ----
#define PREP_X_   5904   // 123*24*512/256
#define PREP_WQ_  864    // 18*24*512/256
#define PREP_WP_  288    // 6*24*512/256
#define PREP_BT_  2814   // ceil(12*245*245/256)
#define PREP_G_   768    // B_*H_
__global__ __launch_bounds__(256) void prep_kernel(
    const float* __restrict__ x, const float* __restrict__ qkv_w,
    const float* __restrict__ proj_w, const float* __restrict__ rpe_table,
    const int* __restrict__ rpe_index, const float* __restrict__ boxmask,
    const float* __restrict__ box_w,
    ushort* __restrict__ ximg, ushort* __restrict__ wqkvimg, ushort* __restrict__ wprojimg,
    ushort* __restrict__ biasTb, float* __restrict__ G, int rpe_m)
{
  __shared__ float bms[NT_][65];
  __shared__ float bws[H_][65];
  int id = blockIdx.x;
  const int tid = threadIdx.x;
  if (id < PREP_X_)  { split_dev(x,      ximg,     M_,  C_, id*256 + tid); return; }
  id -= PREP_X_;
  if (id < PREP_WQ_) { split_dev(qkv_w,  wqkvimg,  C3_, C_, id*256 + tid); return; }
  id -= PREP_WQ_;
  if (id < PREP_WP_) { split_dev(proj_w, wprojimg, C_,  C_, id*256 + tid); return; }
  id -= PREP_WP_;
  if (id < PREP_BT_) {
    int idx = id*256 + tid;
    if (idx < H_*N_*N_) {
      int h = idx / (N_*N_);
      int rem = idx % (N_*N_);
      int i = rem / N_, j = rem % N_;   // j fastest: coalesced idx read + biasTb write
      biasTb[((size_t)h*NPAD_ + i)*NPAD_ + j] = f2bf(rpe_table[h*rpe_m + rpe_index[i*N_ + j]]);
    }
    return;
  }
  id -= PREP_BT_;
  // G role: id = b*12 + ht
  {
    const int b = id / H_, ht = id % H_;
    for (int idx = tid; idx < NT_*64; idx += 256) {
      int j = idx >> 6, d = idx & 63;
      bms[j][d] = boxmask[((size_t)(b*NT_ + j))*C_ + ht*64 + d];
    }
    for (int idx = tid; idx < H_*64; idx += 256) {
      int h = idx >> 6, d = idx & 63;
      bws[h][d] = box_w[(size_t)h*C_ + ht*64 + d];
    }
    __syncthreads();
    for (int o = tid; o < H_*64; o += 256) {
      int h = o >> 6, j = o & 63;
      float s = 0.f;
      if (j < NT_) {
        #pragma unroll
        for (int d = 0; d < 64; ++d) s = fmaf(bws[h][d], bms[j][d], s);
      }
      G[(size_t)id*H_*64 + o] = s;
    }
  }
}

// ---- stage one 16KB tile linearly into LDS ----
__device__ __forceinline__ void stage_tile(const ushort* __restrict__ src, ushort* dst,
                                           int wid, int lane) {
  #pragma unroll
  for (int t = 0; t < 4; ++t) {
    const int o = (wid*4 + t) * 512;
    __builtin_amdgcn_global_load_lds(
      (const __attribute__((address_space(1))) unsigned int*)(src + o + lane*8),
      (__attribute__((address_space(3))) unsigned int*)(dst + o),
      16, 0, 0);
  }
}

// ---- bf16x3 GEMM (token-major A): Co = A @ B^T + bias, fp32 out (proj) ----
__global__ __launch_bounds__(256) void gemm3_kernel(
    const ushort* __restrict__ Aimg, const ushort* __restrict__ Bimg,
    const float* __restrict__ bias, float* __restrict__ Co,
    int KB, int Nn, int M)
{
  __shared__ __align__(16) ushort lds[2][16384];
  const int tid = threadIdx.x, lane = tid & 63, wid = tid >> 6;
  const int g = lane >> 4, li = lane & 15;
  const int sid = xcd_swz(blockIdx.x, NWG_PROJ_);
  const int nb = sid % 6, mb = sid / 6;
  const int wr = (wid >> 1) * 64, wc = (wid & 1) * 64;

  const ushort* Abase = Aimg + (size_t)mb * KB * 8192;
  const ushort* Bbase = Bimg + (size_t)nb * KB * 8192;

  f32x4 acc[4][4];
  #pragma unroll
  for (int i = 0; i < 4; ++i)
    #pragma unroll
    for (int j = 0; j < 4; ++j) acc[i][j] = (f32x4){0.f,0.f,0.f,0.f};

  stage_tile(Abase, &lds[0][0],    wid, lane);
  stage_tile(Bbase, &lds[0][8192], wid, lane);
  __syncthreads();

  for (int kb = 0; kb < KB; ++kb) {
    const int cur = kb & 1;
    if (kb + 1 < KB) {
      stage_tile(Abase + (size_t)(kb+1)*8192, &lds[cur^1][0],    wid, lane);
      stage_tile(Bbase + (size_t)(kb+1)*8192, &lds[cur^1][8192], wid, lane);
    }
    short8 ah[4], al[4], bh[4], bl[4];
    #pragma unroll
    for (int t = 0; t < 4; ++t) {
      const int ra = wr + t*16 + li;
      const ushort* Ar = &lds[cur][ra*64];
      const int ca = (g ^ (ra & 7)) * 8;
      ah[t] = *(const short8*)(Ar + ca);
      al[t] = *(const short8*)(Ar + (ca ^ 32));
      const int rb = wc + t*16 + li;
      const ushort* Br = &lds[cur][8192 + rb*64];
      const int cb = (g ^ (rb & 7)) * 8;
      bh[t] = *(const short8*)(Br + cb);
      bl[t] = *(const short8*)(Br + (cb ^ 32));
    }
    #pragma unroll
    for (int i = 0; i < 4; ++i)
      #pragma unroll
      for (int j = 0; j < 4; ++j) {
        acc[i][j] = __builtin_amdgcn_mfma_f32_16x16x32_bf16(ah[i], bh[j], acc[i][j], 0,0,0);
        acc[i][j] = __builtin_amdgcn_mfma_f32_16x16x32_bf16(al[i], bh[j], acc[i][j], 0,0,0);
        acc[i][j] = __builtin_amdgcn_mfma_f32_16x16x32_bf16(ah[i], bl[j], acc[i][j], 0,0,0);
      }
    __syncthreads();
  }

  #pragma unroll
  for (int i = 0; i < 4; ++i) {
    const int m0 = mb*128 + wr + i*16 + g*4;
    #pragma unroll
    for (int j = 0; j < 4; ++j) {
      const int n = nb*128 + wc + j*16 + li;
      const float bv = bias[n];
      #pragma unroll
      for (int rr = 0; rr < 4; ++rr) {
        const int m = m0 + rr;
        if (m < M) Co[(size_t)m * Nn + n] = acc[i][j][rr] + bv;
      }
    }
  }
}

// ---- bf16x3 QKV GEMM (W-major A): writes bf16 Q/K/VT images directly ----
// VT image is subtiled [dt 4][jc 8][dr 16][kk 32] per head for coalesced PV fragment reads.
__global__ __launch_bounds__(256) void gemm3_qkv_kernel(
    const ushort* __restrict__ Aimg, const ushort* __restrict__ Bimg,
    const float* __restrict__ bias,
    ushort* __restrict__ Qimg, ushort* __restrict__ Kimg, ushort* __restrict__ VTimg,
    int KB)
{
  __shared__ __align__(16) ushort lds[2][16384];
  const int tid = threadIdx.x, lane = tid & 63, wid = tid >> 6;
  const int g = lane >> 4, li = lane & 15;
  const int sid = xcd_swz(blockIdx.x, NWG_QKV_);
  const int mb = sid % 18, nb = sid / 18;   // mb: channel block (fastest), nb: token block
  const int wr = (wid >> 1) * 64, wc = (wid & 1) * 64;

  const ushort* Abase = Aimg + (size_t)mb * KB * 8192;
  const ushort* Bbase = Bimg + (size_t)nb * KB * 8192;

  f32x4 acc[4][4];
  #pragma unroll
  for (int i = 0; i < 4; ++i)
    #pragma unroll
    for (int j = 0; j < 4; ++j) acc[i][j] = (f32x4){0.f,0.f,0.f,0.f};

  stage_tile(Abase, &lds[0][0],    wid, lane);
  stage_tile(Bbase, &lds[0][8192], wid, lane);
  __syncthreads();

  for (int kb = 0; kb < KB; ++kb) {
    const int cur = kb & 1;
    if (kb + 1 < KB) {
      stage_tile(Abase + (size_t)(kb+1)*8192, &lds[cur^1][0],    wid, lane);
      stage_tile(Bbase + (size_t)(kb+1)*8192, &lds[cur^1][8192], wid, lane);
    }
    short8 ah[4], al[4], bh[4], bl[4];
    #pragma unroll
    for (int t = 0; t < 4; ++t) {
      const int ra = wr + t*16 + li;
      const ushort* Ar = &lds[cur][ra*64];
      const int ca = (g ^ (ra & 7)) * 8;
      ah[t] = *(const short8*)(Ar + ca);
      al[t] = *(const short8*)(Ar + (ca ^ 32));
      const int rb = wc + t*16 + li;
      const ushort* Br = &lds[cur][8192 + rb*64];
      const int cb = (g ^ (rb & 7)) * 8;
      bh[t] = *(const short8*)(Br + cb);
      bl[t] = *(const short8*)(Br + (cb ^ 32));
    }
    #pragma unroll
    for (int i = 0; i < 4; ++i)
      #pragma unroll
      for (int j = 0; j < 4; ++j) {
        acc[i][j] = __builtin_amdgcn_mfma_f32_16x16x32_bf16(ah[i], bh[j], acc[i][j], 0,0,0);
        acc[i][j] = __builtin_amdgcn_mfma_f32_16x16x32_bf16(al[i], bh[j], acc[i][j], 0,0,0);
        acc[i][j] = __builtin_amdgcn_mfma_f32_16x16x32_bf16(ah[i], bl[j], acc[i][j], 0,0,0);
      }
    __syncthreads();
  }

  // epilogue: quad = channels ch0..ch0+3 at one token per (j,li)
  #pragma unroll
  for (int i = 0; i < 4; ++i) {
    const int ch0 = mb*128 + wr + i*16 + g*4;
    const int part = ch0 / 768;           // 0=q 1=k 2=v (uniform within quad/tile)
    const int rem  = ch0 - part*768;
    const int h = rem >> 6, d0 = rem & 63;
    const float b0 = bias[ch0+0], b1 = bias[ch0+1], b2 = bias[ch0+2], b3 = bias[ch0+3];
    #pragma unroll
    for (int j = 0; j < 4; ++j) {
      const int tok = nb*128 + wc + j*16 + li;
      if (tok < M_) {
        const int b = tok / 245;
        const int jl = tok - b*245;
        const int bh = b*H_ + h;
        if (part == 0) {
          us4 q4 = { f2bf((acc[i][j][0] + b0)*SCALE_), f2bf((acc[i][j][1] + b1)*SCALE_),
                     f2bf((acc[i][j][2] + b2)*SCALE_), f2bf((acc[i][j][3] + b3)*SCALE_) };
          *(us4*)(Qimg + ((size_t)bh*NPAD_ + jl)*64 + d0) = q4;
        } else if (part == 1) {
          us4 k4 = { f2bf(acc[i][j][0] + b0), f2bf(acc[i][j][1] + b1),
                     f2bf(acc[i][j][2] + b2), f2bf(acc[i][j][3] + b3) };
          *(us4*)(Kimg + ((size_t)bh*NPAD_ + jl)*64 + (d0 ^ ((jl&7)<<3))) = k4;
        } else {
          // tiled VT: [dt][jc][dr][kk], subtile contiguous 512 ushorts
          const int dt = d0 >> 4, dr = d0 & 15;
          const int jc2 = jl >> 5, kk = jl & 31;
          ushort* vb = VTimg + (size_t)bh*16384 + ((dt*8 + jc2)*16 + dr)*32 + kk;
          vb[0]  = f2bf(acc[i][j][0] + b0);
          vb[32] = f2bf(acc[i][j][1] + b1);
          vb[64] = f2bf(acc[i][j][2] + b2);
          vb[96] = f2bf(acc[i][j][3] + b3);
        }
      }
    }
  }
}

// -------- template attention (MFMA) -> F_part[b,h,i,ht] = sum_j P[i,j]*G[b,ht,h,j] --------
__global__ __launch_bounds__(256) void tmpl_kernel(
    const ushort* __restrict__ Qimg, const ushort* __restrict__ Kimg,
    const float* __restrict__ G, const ushort* __restrict__ biasTb,
    float* __restrict__ F_part)
{
  __shared__ __align__(16) ushort kt_lds[64*64];   // first 64 K rows (swizzled image)
  __shared__ __align__(16) float Gs[H_*64];
  const int bx = blockIdx.x;       // b*12 + ht
  const int b = bx / H_, ht = bx % H_;
  const int tid = threadIdx.x, lane = tid & 63, wid = tid >> 6;
  const int g = lane >> 4, li = lane & 15;

  const ushort* Kb = Kimg + (size_t)bx*NPAD_*64;
  #pragma unroll
  for (int t = 0; t < 2; ++t) {
    const int o = (t*4 + wid) * 512;
    __builtin_amdgcn_global_load_lds(
      (const __attribute__((address_space(1))) unsigned int*)(Kb + o + lane*8),
      (__attribute__((address_space(3))) unsigned int*)(kt_lds + o), 16, 0, 0);
  }
  for (int idx = tid; idx < H_*64; idx += 256) Gs[idx] = G[(size_t)bx*H_*64 + idx];

  const int i = wid*16 + li;       // q-row 0..63 (template rows are 0..48)
  short8 bq[2];
  {
    const ushort* qp = Qimg + ((size_t)bx*NPAD_ + i)*64;   // Q pre-scaled
    bq[0] = *(const short8*)(qp + g*8);
    bq[1] = *(const short8*)(qp + 32 + g*8);
  }
  __syncthreads();

  f32x4 sacc[4];
  #pragma unroll
  for (int jt = 0; jt < 4; ++jt) sacc[jt] = (f32x4){0.f,0.f,0.f,0.f};
  #pragma unroll
  for (int jt = 0; jt < 4; ++jt) {
    int jr = jt*16 + li;
    #pragma unroll
    for (int kc = 0; kc < 2; ++kc) {
      short8 af = *(const short8*)(kt_lds + jr*64 + ((kc*32 + g*8) ^ ((jr&7)<<3)));
      sacc[jt] = __builtin_amdgcn_mfma_f32_16x16x32_bf16(af, bq[kc], sacc[jt], 0, 0, 0);
    }
  }

  const ushort* bT = biasTb + (size_t)ht*NPAD_*NPAD_ + (size_t)i*NPAD_;   // i-major
  float mloc = 0.f;                 // masked zeros join the max
  #pragma unroll
  for (int jt = 0; jt < 4; ++jt) {
    us4 b4 = *(const us4*)(bT + jt*16 + g*4);
    #pragma unroll
    for (int r = 0; r < 4; ++r) {
      int j = jt*16 + g*4 + r;
      float sv = (j < NT_) ? (sacc[jt][r] + bf2f(b4[r])) : -1e30f;
      sacc[jt][r] = sv;
      mloc = fmaxf(mloc, sv);
    }
  }
  mloc = fmaxf(mloc, __shfl_xor(mloc, 16));
  mloc = fmaxf(mloc, __shfl_xor(mloc, 32));
  float ssum = 0.f;
  #pragma unroll
  for (int jt = 0; jt < 4; ++jt)
    #pragma unroll
    for (int r = 0; r < 4; ++r) {
      int j = jt*16 + g*4 + r;
      float e = (j < NT_) ? __expf(sacc[jt][r] - mloc) : 0.f;
      sacc[jt][r] = e;
      ssum += e;
    }
  ssum += __shfl_xor(ssum, 16);
  ssum += __shfl_xor(ssum, 32);
  const float inv = 1.f / (ssum + 196.f * __expf(-mloc));   // 196 masked exp(0-mx)

  float F[12];
  #pragma unroll
  for (int h = 0; h < 12; ++h) F[h] = 0.f;
  #pragma unroll
  for (int jt = 0; jt < 4; ++jt) {
    f32x4 p = sacc[jt] * inv;
    #pragma unroll
    for (int h = 0; h < 12; ++h) {
      const float4 g4 = *(const float4*)(&Gs[h*64 + jt*16 + g*4]);
      F[h] = fmaf(p[0], g4.x, fmaf(p[1], g4.y, fmaf(p[2], g4.z, fmaf(p[3], g4.w, F[h]))));
    }
  }
  #pragma unroll
  for (int h = 0; h < 12; ++h) {
    F[h] += __shfl_xor(F[h], 16);
    F[h] += __shfl_xor(F[h], 32);
  }
  if (lane < 16 && i < NT_) {
    #pragma unroll
    for (int h = 0; h < 12; ++h)
      F_part[((size_t)(b*H_ + h)*NT_ + i)*12 + ht] = F[h];
  }
}

// -------- MFMA flash attention; V read coalesced from tiled VT image --------
__global__ __launch_bounds__(256) void attn_mfma_kernel(
    const ushort* __restrict__ Qimg, const ushort* __restrict__ Kimg,
    const ushort* __restrict__ VTimg, const ushort* __restrict__ biasTb,
    const float* __restrict__ F_part, const float* __restrict__ box_b,
    ushort* __restrict__ attnimg)
{
  __shared__ __align__(16) ushort kp_lds[NPAD_*64];   // K image; then P; then O-transpose
  const int bx = blockIdx.x;
  const int bh = bx >> 2, rb = bx & 3;
  const int b = bh / H_, h = bh % H_;
  const int tid = threadIdx.x, lane = tid & 63, wid = tid >> 6;
  const int g = lane >> 4, li = lane & 15;

  const ushort* Kb = Kimg  + (size_t)bh*16384;
  const ushort* Vb = VTimg + (size_t)bh*16384;
  #pragma unroll
  for (int t = 0; t < 8; ++t) {
    const int o = (t*4 + wid) * 512;
    __builtin_amdgcn_global_load_lds(
      (const __attribute__((address_space(1))) unsigned int*)(Kb + o + lane*8),
      (__attribute__((address_space(3))) unsigned int*)(kp_lds + o), 16, 0, 0);
  }

  const int i0 = rb*64 + wid*16;
  const int ig = i0 + li;
  const int iq = (ig < N_) ? ig : (N_-1);
  short8 bq[2];
  {
    const ushort* qp = Qimg + ((size_t)bh*NPAD_ + iq)*64;   // Q pre-scaled
    bq[0] = *(const short8*)(qp + g*8);
    bq[1] = *(const short8*)(qp + 32 + g*8);
  }
  __syncthreads();

  f32x4 sacc[16];
  #pragma unroll
  for (int jt = 0; jt < 16; ++jt) sacc[jt] = (f32x4){0.f,0.f,0.f,0.f};
  #pragma unroll
  for (int jt = 0; jt < 16; ++jt) {
    int jr = jt*16 + li;
    #pragma unroll
    for (int kc = 0; kc < 2; ++kc) {
      short8 af = *(const short8*)(kp_lds + jr*64 + ((kc*32 + g*8) ^ ((jr&7)<<3)));
      sacc[jt] = __builtin_amdgcn_mfma_f32_16x16x32_bf16(af, bq[kc], sacc[jt], 0, 0, 0);
    }
  }
  __syncthreads();   // all waves done reading K; kp_lds becomes P

  float fac = 1.0f;
  if (ig < NT_) {
    const float* fp = F_part + ((size_t)bh*NT_ + ig)*12;
    float4 f0 = *(const float4*)fp;
    float4 f1 = *(const float4*)(fp+4);
    float4 f2 = *(const float4*)(fp+8);
    fac = box_b[h] + f0.x+f0.y+f0.z+f0.w + f1.x+f1.y+f1.z+f1.w + f2.x+f2.y+f2.z+f2.w;
  }
  const ushort* bT = biasTb + (size_t)h*NPAD_*NPAD_ + (size_t)(i0 + li)*NPAD_;  // i-major
  float mloc = -1e30f;
  #pragma unroll
  for (int jt = 0; jt < 16; ++jt) {
    us4 b4 = *(const us4*)(bT + jt*16 + g*4);
    #pragma unroll
    for (int r = 0; r < 4; ++r) {
      int j = jt*16 + g*4 + r;
      float sv = sacc[jt][r] + bf2f(b4[r]);
      if (ig < NT_ && j >= NT_) sv *= fac;
      if (j >= N_) sv = -1e30f;
      sacc[jt][r] = sv;
      mloc = fmaxf(mloc, sv);
    }
  }
  mloc = fmaxf(mloc, __shfl_xor(mloc, 16));
  mloc = fmaxf(mloc, __shfl_xor(mloc, 32));
  float ssum = 0.f;
  #pragma unroll
  for (int jt = 0; jt < 16; ++jt) {
    #pragma unroll
    for (int r = 0; r < 4; ++r) {
      float e = __expf(sacc[jt][r] - mloc);
      sacc[jt][r] = e;
      ssum += e;
    }
  }
  ssum += __shfl_xor(ssum, 16);
  ssum += __shfl_xor(ssum, 32);
  const float inv = 1.0f / ssum;

  ushort* pbase = kp_lds + wid*4096 + li*256;
  const int swz = (li & 7) << 3;
  #pragma unroll
  for (int jt = 0; jt < 16; ++jt) {
    unsigned w0 = (unsigned)f2bf(sacc[jt][0]*inv) | ((unsigned)f2bf(sacc[jt][1]*inv) << 16);
    unsigned w1 = (unsigned)f2bf(sacc[jt][2]*inv) | ((unsigned)f2bf(sacc[jt][3]*inv) << 16);
    *(uint2*)(pbase + ((jt*16 + g*4) ^ swz)) = make_uint2(w0, w1);
  }

  f32x4 oacc[4];
  #pragma unroll
  for (int dt = 0; dt < 4; ++dt) oacc[dt] = (f32x4){0.f,0.f,0.f,0.f};
  #pragma unroll
  for (int jc = 0; jc < 8; ++jc) {
    short8 pf = *(const short8*)(pbase + ((jc*32 + g*8) ^ swz));
    #pragma unroll
    for (int dt = 0; dt < 4; ++dt) {
      // tiled VT read: contiguous 1KB per wave fragment
      short8 vf = *(const short8*)(Vb + (dt*8 + jc)*512 + li*32 + g*8);
      oacc[dt] = __builtin_amdgcn_mfma_f32_16x16x32_bf16(vf, pf, oacc[dt], 0, 0, 0);
    }
  }

  // ---- per-wave LDS transpose in own 8KB region (no barrier needed) ----
  float* tb = (float*)(kp_lds + wid*4096);
  #pragma unroll
  for (int dt = 0; dt < 4; ++dt)
    #pragma unroll
    for (int rr = 0; rr < 4; ++rr)
      tb[(dt*16 + g*4 + rr)*19 + li] = oacc[dt][rr];

  const int rtok = lane >> 2, cg = lane & 3;
  const int tokl = i0 + rtok;
  if (tokl < N_) {
    const int m = b*N_ + tokl;
    const int mbm = m >> 7, rr_ = m & 127, rx = rr_ & 7;
    const int kbb = h*2 + (cg >> 1);
    ushort* baseimg = attnimg + (((size_t)(mbm*KB_ + kbb))*128 + rr_)*64;
    #pragma unroll
    for (int half = 0; half < 2; ++half) {
      us8 hv, lv;
      #pragma unroll
      for (int e = 0; e < 8; ++e) {
        float v = tb[(cg*16 + half*8 + e)*19 + rtok];
        ushort hh, ll; split2(v, hh, ll);
        hv[e] = hh; lv[e] = ll;
      }
      const int c0 = (cg & 1)*2 + half;
      *(us8*)(baseimg + ((c0 ^ rx) * 8))        = hv;
      *(us8*)(baseimg + (((c0 ^ 4) ^ rx) * 8))  = lv;
    }
  }
}

extern "C" void kernel_launch(void* const* d_in, const int* in_sizes, int n_in,
                              void* d_out, int out_size, void* d_ws, size_t ws_size,
                              hipStream_t stream)
{
  const float* x         = (const float*)d_in[0];
  const float* boxmask   = (const float*)d_in[1];
  const float* qkv_w     = (const float*)d_in[2];
  const float* qkv_b     = (const float*)d_in[3];
  const float* proj_w    = (const float*)d_in[4];
  const float* proj_b    = (const float*)d_in[5];
  const float* box_w     = (const float*)d_in[6];
  const float* box_b     = (const float*)d_in[7];
  const float* rpe_table = (const float*)d_in[8];
  const int*   rpe_index = (const int*)d_in[9];
  const int rpe_m = in_sizes[8] / H_;   // 1698

  float* ws      = (float*)d_ws;
  float* G       = ws;                                   // 589,824 f
  float* F_part  = G + (size_t)B_*H_*H_*64;              // 451,584 f
  ushort* biasTb = (ushort*)(F_part + (size_t)B_*H_*NT_*12);  // 786,432 us
  ushort* ximg    = biasTb   + (size_t)H_*NPAD_*NPAD_;
  ushort* wqkvimg  = ximg     + (size_t)MP_*C_*2;        // 24,182,784 us
  ushort* wprojimg = wqkvimg  + (size_t)C3_*C_*2;        // 3,538,944 us
  ushort* Qimg     = wprojimg + (size_t)C_*C_*2;         // 1,179,648 us
  ushort* Kimg     = Qimg     + (size_t)B_*H_*NPAD_*64;  // 12,582,912 us each
  ushort* VTimg    = Kimg     + (size_t)B_*H_*NPAD_*64;
  ushort* attnimg  = ximg;   // alias: x image dead after QKV GEMM
  float* out     = (float*)d_out;

  // 0) merged prep: splits + bf16 biasT (i-major) + G
  prep_kernel<<<PREP_X_+PREP_WQ_+PREP_WP_+PREP_BT_+PREP_G_, 256, 0, stream>>>(
      x, qkv_w, proj_w, rpe_table, rpe_index, boxmask, box_w,
      ximg, wqkvimg, wprojimg, biasTb, G, rpe_m);
  // 1) QKV projection -> bf16 Q/K/VT images (XCD-swizzled 1D grid)
  gemm3_qkv_kernel<<<NWG_QKV_, 256, 0, stream>>>(wqkvimg, ximg, qkv_b, Qimg, Kimg, VTimg, KB_);
  // 2) template attention (MFMA) -> F_part
  tmpl_kernel<<<B_*H_, 256, 0, stream>>>(Qimg, Kimg, G, biasTb, F_part);
  // 3) MFMA attention -> attn image
  attn_mfma_kernel<<<B_*H_*4, 256, 0, stream>>>(Qimg, Kimg, VTimg, biasTb, F_part, box_b, attnimg);
  // 4) output projection (bf16x3 MFMA, fp32 out, XCD-swizzled)
  gemm3_kernel<<<NWG_PROJ_, 256, 0, stream>>>(attnimg, wprojimg, proj_b, out, KB_, C_, M_);
}

// Round 12
// 425.344 us; speedup vs baseline: 1.0459x; 1.0456x over previous
//
#include <hip/hip_runtime.h>
#include <hip/hip_bf16.h>

#define B_ 64
#define N_ 245
#define NT_ 49
#define H_ 12
#define HD_ 64
#define C_ 768
#define C3_ 2304
#define M_ (B_*N_)         // 15680 tokens
#define MP_ 15744          // padded to 123*128
#define MB_ 123
#define KB_ 24             // 768/32 k-blocks
#define SCALE_ 0.125f
#define NPAD_ 256
#define NWG_QKV_ (18*123)  // 2214
#define NWG_PROJ_ (6*123)  // 738

typedef short short8 __attribute__((ext_vector_type(8)));
typedef float f32x4 __attribute__((ext_vector_type(4)));
typedef ushort us8 __attribute__((ext_vector_type(8)));
typedef ushort us4 __attribute__((ext_vector_type(4)));

__device__ __forceinline__ ushort f2bf(float f) {   // fp32 -> bf16 RTN
  unsigned u = __builtin_bit_cast(unsigned, f);
  u += 0x7fffu + ((u >> 16) & 1u);
  return (ushort)(u >> 16);
}
__device__ __forceinline__ float bf2f(ushort u) {
  return __builtin_bit_cast(float, ((unsigned)u) << 16);
}
// split a = hi + lo (both bf16; dropped error ~2^-16 relative)
__device__ __forceinline__ void split2(float a, ushort& hi, ushort& lo) {
  unsigned u = __builtin_bit_cast(unsigned, a);
  hi = (ushort)(u >> 16);
  float hf = __builtin_bit_cast(float, u & 0xffff0000u);
  lo = (ushort)(__builtin_bit_cast(unsigned, a - hf) >> 16);
}
// m204 bijective XCD swizzle
__device__ __forceinline__ int xcd_swz(int orig, int nwg) {
  const int q = nwg >> 3, r = nwg & 7;
  const int xcd = orig & 7, off = orig >> 3;
  return (xcd < r ? xcd*(q+1) : r*(q+1) + (xcd-r)*q) + off;
}

// ---- split one 8-elem chunk into the pre-tiled pre-swizzled hi|lo image ----
__device__ __forceinline__ void split_dev(
    const float* __restrict__ A, ushort* __restrict__ img, int rows, int K, int idx)
{
  const int ch = idx & 3;
  const int r  = (idx >> 2) & 127;
  const int t  = idx >> 9;
  const int KBl = K >> 5;
  const int kb = t % KBl, mb = t / KBl;
  const int m = mb*128 + r;
  float4 v0 = make_float4(0,0,0,0), v1 = make_float4(0,0,0,0);
  if (m < rows) {
    const float* p = A + (size_t)m*K + kb*32 + ch*8;
    v0 = *(const float4*)p; v1 = *(const float4*)(p+4);
  }
  float vals[8] = {v0.x,v0.y,v0.z,v0.w,v1.x,v1.y,v1.z,v1.w};
  us8 hv, lv;
  #pragma unroll
  for (int e = 0; e < 8; ++e) { ushort hh, ll; split2(vals[e], hh, ll); hv[e]=hh; lv[e]=ll; }
  ushort* base = img + ((size_t)t*128 + r)*64;
  const int sw = (ch ^ (r&7))*8;
  *(us8*)(base + sw)        = hv;
  *(us8*)(base + (sw ^ 32)) = lv;
}

// ---- merged prep: x/w splits + bf16 biasT gather (i-major) + G GEMV ----
#define PREP_X_   5904   // 123*24*512/256
#define PREP_WQ_  864    // 18*24*512/256
#define PREP_WP_  288    // 6*24*512/256
#define PREP_BT_  2814   // ceil(12*245*245/256)
#define PREP_G_   768    // B_*H_
__global__ __launch_bounds__(256) void prep_kernel(
    const float* __restrict__ x, const float* __restrict__ qkv_w,
    const float* __restrict__ proj_w, const float* __restrict__ rpe_table,
    const int* __restrict__ rpe_index, const float* __restrict__ boxmask,
    const float* __restrict__ box_w,
    ushort* __restrict__ ximg, ushort* __restrict__ wqkvimg, ushort* __restrict__ wprojimg,
    ushort* __restrict__ biasTb, float* __restrict__ G, int rpe_m)
{
  __shared__ float bms[NT_][65];
  __shared__ float bws[H_][65];
  int id = blockIdx.x;
  const int tid = threadIdx.x;
  if (id < PREP_X_)  { split_dev(x,      ximg,     M_,  C_, id*256 + tid); return; }
  id -= PREP_X_;
  if (id < PREP_WQ_) { split_dev(qkv_w,  wqkvimg,  C3_, C_, id*256 + tid); return; }
  id -= PREP_WQ_;
  if (id < PREP_WP_) { split_dev(proj_w, wprojimg, C_,  C_, id*256 + tid); return; }
  id -= PREP_WP_;
  if (id < PREP_BT_) {
    int idx = id*256 + tid;
    if (idx < H_*N_*N_) {
      int h = idx / (N_*N_);
      int rem = idx % (N_*N_);
      int i = rem / N_, j = rem % N_;   // j fastest: coalesced idx read + biasTb write
      biasTb[((size_t)h*NPAD_ + i)*NPAD_ + j] = f2bf(rpe_table[h*rpe_m + rpe_index[i*N_ + j]]);
    }
    return;
  }
  id -= PREP_BT_;
  // G role: id = b*12 + ht
  {
    const int b = id / H_, ht = id % H_;
    for (int idx = tid; idx < NT_*64; idx += 256) {
      int j = idx >> 6, d = idx & 63;
      bms[j][d] = boxmask[((size_t)(b*NT_ + j))*C_ + ht*64 + d];
    }
    for (int idx = tid; idx < H_*64; idx += 256) {
      int h = idx >> 6, d = idx & 63;
      bws[h][d] = box_w[(size_t)h*C_ + ht*64 + d];
    }
    __syncthreads();
    for (int o = tid; o < H_*64; o += 256) {
      int h = o >> 6, j = o & 63;
      float s = 0.f;
      if (j < NT_) {
        #pragma unroll
        for (int d = 0; d < 64; ++d) s = fmaf(bws[h][d], bms[j][d], s);
      }
      G[(size_t)id*H_*64 + o] = s;
    }
  }
}

// ---- stage one 16KB tile linearly into LDS ----
__device__ __forceinline__ void stage_tile(const ushort* __restrict__ src, ushort* dst,
                                           int wid, int lane) {
  #pragma unroll
  for (int t = 0; t < 4; ++t) {
    const int o = (wid*4 + t) * 512;
    __builtin_amdgcn_global_load_lds(
      (const __attribute__((address_space(1))) unsigned int*)(src + o + lane*8),
      (__attribute__((address_space(3))) unsigned int*)(dst + o),
      16, 0, 0);
  }
}

// ---- bf16x3 GEMM (token-major A): Co = A @ B^T + bias, fp32 out (proj) ----
__global__ __launch_bounds__(256) void gemm3_kernel(
    const ushort* __restrict__ Aimg, const ushort* __restrict__ Bimg,
    const float* __restrict__ bias, float* __restrict__ Co,
    int KB, int Nn, int M)
{
  __shared__ __align__(16) ushort lds[2][16384];
  const int tid = threadIdx.x, lane = tid & 63, wid = tid >> 6;
  const int g = lane >> 4, li = lane & 15;
  const int sid = xcd_swz(blockIdx.x, NWG_PROJ_);
  const int nb = sid % 6, mb = sid / 6;
  const int wr = (wid >> 1) * 64, wc = (wid & 1) * 64;

  const ushort* Abase = Aimg + (size_t)mb * KB * 8192;
  const ushort* Bbase = Bimg + (size_t)nb * KB * 8192;

  f32x4 acc[4][4];
  #pragma unroll
  for (int i = 0; i < 4; ++i)
    #pragma unroll
    for (int j = 0; j < 4; ++j) acc[i][j] = (f32x4){0.f,0.f,0.f,0.f};

  stage_tile(Abase, &lds[0][0],    wid, lane);
  stage_tile(Bbase, &lds[0][8192], wid, lane);
  __syncthreads();

  for (int kb = 0; kb < KB; ++kb) {
    const int cur = kb & 1;
    if (kb + 1 < KB) {
      stage_tile(Abase + (size_t)(kb+1)*8192, &lds[cur^1][0],    wid, lane);
      stage_tile(Bbase + (size_t)(kb+1)*8192, &lds[cur^1][8192], wid, lane);
    }
    short8 ah[4], al[4], bh[4], bl[4];
    #pragma unroll
    for (int t = 0; t < 4; ++t) {
      const int ra = wr + t*16 + li;
      const ushort* Ar = &lds[cur][ra*64];
      const int ca = (g ^ (ra & 7)) * 8;
      ah[t] = *(const short8*)(Ar + ca);
      al[t] = *(const short8*)(Ar + (ca ^ 32));
      const int rb = wc + t*16 + li;
      const ushort* Br = &lds[cur][8192 + rb*64];
      const int cb = (g ^ (rb & 7)) * 8;
      bh[t] = *(const short8*)(Br + cb);
      bl[t] = *(const short8*)(Br + (cb ^ 32));
    }
    #pragma unroll
    for (int i = 0; i < 4; ++i)
      #pragma unroll
      for (int j = 0; j < 4; ++j) {
        acc[i][j] = __builtin_amdgcn_mfma_f32_16x16x32_bf16(ah[i], bh[j], acc[i][j], 0,0,0);
        acc[i][j] = __builtin_amdgcn_mfma_f32_16x16x32_bf16(al[i], bh[j], acc[i][j], 0,0,0);
        acc[i][j] = __builtin_amdgcn_mfma_f32_16x16x32_bf16(ah[i], bl[j], acc[i][j], 0,0,0);
      }
    __syncthreads();
  }

  #pragma unroll
  for (int i = 0; i < 4; ++i) {
    const int m0 = mb*128 + wr + i*16 + g*4;
    #pragma unroll
    for (int j = 0; j < 4; ++j) {
      const int n = nb*128 + wc + j*16 + li;
      const float bv = bias[n];
      #pragma unroll
      for (int rr = 0; rr < 4; ++rr) {
        const int m = m0 + rr;
        if (m < M) Co[(size_t)m * Nn + n] = acc[i][j][rr] + bv;
      }
    }
  }
}

// ---- bf16x3 QKV GEMM (W-major A): writes bf16 Q/K/VT images directly ----
// VT image: round-8 layout [d 64][j 256] with XOR swizzle (^(d&7)<<3 on j).
__global__ __launch_bounds__(256) void gemm3_qkv_kernel(
    const ushort* __restrict__ Aimg, const ushort* __restrict__ Bimg,
    const float* __restrict__ bias,
    ushort* __restrict__ Qimg, ushort* __restrict__ Kimg, ushort* __restrict__ VTimg,
    int KB)
{
  __shared__ __align__(16) ushort lds[2][16384];
  const int tid = threadIdx.x, lane = tid & 63, wid = tid >> 6;
  const int g = lane >> 4, li = lane & 15;
  const int sid = xcd_swz(blockIdx.x, NWG_QKV_);
  const int mb = sid % 18, nb = sid / 18;   // mb: channel block (fastest), nb: token block
  const int wr = (wid >> 1) * 64, wc = (wid & 1) * 64;

  const ushort* Abase = Aimg + (size_t)mb * KB * 8192;
  const ushort* Bbase = Bimg + (size_t)nb * KB * 8192;

  f32x4 acc[4][4];
  #pragma unroll
  for (int i = 0; i < 4; ++i)
    #pragma unroll
    for (int j = 0; j < 4; ++j) acc[i][j] = (f32x4){0.f,0.f,0.f,0.f};

  stage_tile(Abase, &lds[0][0],    wid, lane);
  stage_tile(Bbase, &lds[0][8192], wid, lane);
  __syncthreads();

  for (int kb = 0; kb < KB; ++kb) {
    const int cur = kb & 1;
    if (kb + 1 < KB) {
      stage_tile(Abase + (size_t)(kb+1)*8192, &lds[cur^1][0],    wid, lane);
      stage_tile(Bbase + (size_t)(kb+1)*8192, &lds[cur^1][8192], wid, lane);
    }
    short8 ah[4], al[4], bh[4], bl[4];
    #pragma unroll
    for (int t = 0; t < 4; ++t) {
      const int ra = wr + t*16 + li;
      const ushort* Ar = &lds[cur][ra*64];
      const int ca = (g ^ (ra & 7)) * 8;
      ah[t] = *(const short8*)(Ar + ca);
      al[t] = *(const short8*)(Ar + (ca ^ 32));
      const int rb = wc + t*16 + li;
      const ushort* Br = &lds[cur][8192 + rb*64];
      const int cb = (g ^ (rb & 7)) * 8;
      bh[t] = *(const short8*)(Br + cb);
      bl[t] = *(const short8*)(Br + (cb ^ 32));
    }
    #pragma unroll
    for (int i = 0; i < 4; ++i)
      #pragma unroll
      for (int j = 0; j < 4; ++j) {
        acc[i][j] = __builtin_amdgcn_mfma_f32_16x16x32_bf16(ah[i], bh[j], acc[i][j], 0,0,0);
        acc[i][j] = __builtin_amdgcn_mfma_f32_16x16x32_bf16(al[i], bh[j], acc[i][j], 0,0,0);
        acc[i][j] = __builtin_amdgcn_mfma_f32_16x16x32_bf16(ah[i], bl[j], acc[i][j], 0,0,0);
      }
    __syncthreads();
  }

  // epilogue: quad = channels ch0..ch0+3 at one token per (j,li)
  #pragma unroll
  for (int i = 0; i < 4; ++i) {
    const int ch0 = mb*128 + wr + i*16 + g*4;
    const int part = ch0 / 768;           // 0=q 1=k 2=v (uniform within quad/tile)
    const int rem  = ch0 - part*768;
    const int h = rem >> 6, d0 = rem & 63;
    const float b0 = bias[ch0+0], b1 = bias[ch0+1], b2 = bias[ch0+2], b3 = bias[ch0+3];
    #pragma unroll
    for (int j = 0; j < 4; ++j) {
      const int tok = nb*128 + wc + j*16 + li;
      if (tok < M_) {
        const int b = tok / 245;
        const int jl = tok - b*245;
        const int bh = b*H_ + h;
        if (part == 0) {
          us4 q4 = { f2bf((acc[i][j][0] + b0)*SCALE_), f2bf((acc[i][j][1] + b1)*SCALE_),
                     f2bf((acc[i][j][2] + b2)*SCALE_), f2bf((acc[i][j][3] + b3)*SCALE_) };
          *(us4*)(Qimg + ((size_t)bh*NPAD_ + jl)*64 + d0) = q4;
        } else if (part == 1) {
          us4 k4 = { f2bf(acc[i][j][0] + b0), f2bf(acc[i][j][1] + b1),
                     f2bf(acc[i][j][2] + b2), f2bf(acc[i][j][3] + b3) };
          *(us4*)(Kimg + ((size_t)bh*NPAD_ + jl)*64 + (d0 ^ ((jl&7)<<3))) = k4;
        } else {
          VTimg[((size_t)bh*64 + d0+0)*NPAD_ + (jl ^ (((d0+0)&7)<<3))] = f2bf(acc[i][j][0] + b0);
          VTimg[((size_t)bh*64 + d0+1)*NPAD_ + (jl ^ (((d0+1)&7)<<3))] = f2bf(acc[i][j][1] + b1);
          VTimg[((size_t)bh*64 + d0+2)*NPAD_ + (jl ^ (((d0+2)&7)<<3))] = f2bf(acc[i][j][2] + b2);
          VTimg[((size_t)bh*64 + d0+3)*NPAD_ + (jl ^ (((d0+3)&7)<<3))] = f2bf(acc[i][j][3] + b3);
        }
      }
    }
  }
}

// -------- template attention (MFMA) -> F_part[b,h,i,ht] = sum_j P[i,j]*G[b,ht,h,j] --------
__global__ __launch_bounds__(256) void tmpl_kernel(
    const ushort* __restrict__ Qimg, const ushort* __restrict__ Kimg,
    const float* __restrict__ G, const ushort* __restrict__ biasTb,
    float* __restrict__ F_part)
{
  __shared__ __align__(16) ushort kt_lds[64*64];   // first 64 K rows (swizzled image)
  __shared__ __align__(16) float Gs[H_*64];
  const int bx = blockIdx.x;       // b*12 + ht
  const int b = bx / H_, ht = bx % H_;
  const int tid = threadIdx.x, lane = tid & 63, wid = tid >> 6;
  const int g = lane >> 4, li = lane & 15;

  const ushort* Kb = Kimg + (size_t)bx*NPAD_*64;
  #pragma unroll
  for (int t = 0; t < 2; ++t) {
    const int o = (t*4 + wid) * 512;
    __builtin_amdgcn_global_load_lds(
      (const __attribute__((address_space(1))) unsigned int*)(Kb + o + lane*8),
      (__attribute__((address_space(3))) unsigned int*)(kt_lds + o), 16, 0, 0);
  }
  for (int idx = tid; idx < H_*64; idx += 256) Gs[idx] = G[(size_t)bx*H_*64 + idx];

  const int i = wid*16 + li;       // q-row 0..63 (template rows are 0..48)
  short8 bq[2];
  {
    const ushort* qp = Qimg + ((size_t)bx*NPAD_ + i)*64;   // Q pre-scaled
    bq[0] = *(const short8*)(qp + g*8);
    bq[1] = *(const short8*)(qp + 32 + g*8);
  }
  __syncthreads();

  f32x4 sacc[4];
  #pragma unroll
  for (int jt = 0; jt < 4; ++jt) sacc[jt] = (f32x4){0.f,0.f,0.f,0.f};
  #pragma unroll
  for (int jt = 0; jt < 4; ++jt) {
    int jr = jt*16 + li;
    #pragma unroll
    for (int kc = 0; kc < 2; ++kc) {
      short8 af = *(const short8*)(kt_lds + jr*64 + ((kc*32 + g*8) ^ ((jr&7)<<3)));
      sacc[jt] = __builtin_amdgcn_mfma_f32_16x16x32_bf16(af, bq[kc], sacc[jt], 0, 0, 0);
    }
  }

  const ushort* bT = biasTb + (size_t)ht*NPAD_*NPAD_ + (size_t)i*NPAD_;   // i-major
  float mloc = 0.f;                 // masked zeros join the max
  #pragma unroll
  for (int jt = 0; jt < 4; ++jt) {
    us4 b4 = *(const us4*)(bT + jt*16 + g*4);
    #pragma unroll
    for (int r = 0; r < 4; ++r) {
      int j = jt*16 + g*4 + r;
      float sv = (j < NT_) ? (sacc[jt][r] + bf2f(b4[r])) : -1e30f;
      sacc[jt][r] = sv;
      mloc = fmaxf(mloc, sv);
    }
  }
  mloc = fmaxf(mloc, __shfl_xor(mloc, 16));
  mloc = fmaxf(mloc, __shfl_xor(mloc, 32));
  float ssum = 0.f;
  #pragma unroll
  for (int jt = 0; jt < 4; ++jt)
    #pragma unroll
    for (int r = 0; r < 4; ++r) {
      int j = jt*16 + g*4 + r;
      float e = (j < NT_) ? __expf(sacc[jt][r] - mloc) : 0.f;
      sacc[jt][r] = e;
      ssum += e;
    }
  ssum += __shfl_xor(ssum, 16);
  ssum += __shfl_xor(ssum, 32);
  const float inv = 1.f / (ssum + 196.f * __expf(-mloc));   // 196 masked exp(0-mx)

  float F[12];
  #pragma unroll
  for (int h = 0; h < 12; ++h) F[h] = 0.f;
  #pragma unroll
  for (int jt = 0; jt < 4; ++jt) {
    f32x4 p = sacc[jt] * inv;
    #pragma unroll
    for (int h = 0; h < 12; ++h) {
      const float4 g4 = *(const float4*)(&Gs[h*64 + jt*16 + g*4]);
      F[h] = fmaf(p[0], g4.x, fmaf(p[1], g4.y, fmaf(p[2], g4.z, fmaf(p[3], g4.w, F[h]))));
    }
  }
  #pragma unroll
  for (int h = 0; h < 12; ++h) {
    F[h] += __shfl_xor(F[h], 16);
    F[h] += __shfl_xor(F[h], 32);
  }
  if (lane < 16 && i < NT_) {
    #pragma unroll
    for (int h = 0; h < 12; ++h)
      F_part[((size_t)(b*H_ + h)*NT_ + i)*12 + ht] = F[h];
  }
}

// -------- MFMA flash attention; V read direct from L2 (round-8 swizzled layout) --------
__global__ __launch_bounds__(256) void attn_mfma_kernel(
    const ushort* __restrict__ Qimg, const ushort* __restrict__ Kimg,
    const ushort* __restrict__ VTimg, const ushort* __restrict__ biasTb,
    const float* __restrict__ F_part, const float* __restrict__ box_b,
    ushort* __restrict__ attnimg)
{
  __shared__ __align__(16) ushort kp_lds[NPAD_*64];   // K image; then P; then O-transpose
  const int bx = blockIdx.x;
  const int bh = bx >> 2, rb = bx & 3;
  const int b = bh / H_, h = bh % H_;
  const int tid = threadIdx.x, lane = tid & 63, wid = tid >> 6;
  const int g = lane >> 4, li = lane & 15;

  const ushort* Kb = Kimg  + (size_t)bh*16384;
  const ushort* Vb = VTimg + (size_t)bh*16384;
  #pragma unroll
  for (int t = 0; t < 8; ++t) {
    const int o = (t*4 + wid) * 512;
    __builtin_amdgcn_global_load_lds(
      (const __attribute__((address_space(1))) unsigned int*)(Kb + o + lane*8),
      (__attribute__((address_space(3))) unsigned int*)(kp_lds + o), 16, 0, 0);
  }

  const int i0 = rb*64 + wid*16;
  const int ig = i0 + li;
  const int iq = (ig < N_) ? ig : (N_-1);
  short8 bq[2];
  {
    const ushort* qp = Qimg + ((size_t)bh*NPAD_ + iq)*64;   // Q pre-scaled
    bq[0] = *(const short8*)(qp + g*8);
    bq[1] = *(const short8*)(qp + 32 + g*8);
  }
  __syncthreads();

  f32x4 sacc[16];
  #pragma unroll
  for (int jt = 0; jt < 16; ++jt) sacc[jt] = (f32x4){0.f,0.f,0.f,0.f};
  #pragma unroll
  for (int jt = 0; jt < 16; ++jt) {
    int jr = jt*16 + li;
    #pragma unroll
    for (int kc = 0; kc < 2; ++kc) {
      short8 af = *(const short8*)(kp_lds + jr*64 + ((kc*32 + g*8) ^ ((jr&7)<<3)));
      sacc[jt] = __builtin_amdgcn_mfma_f32_16x16x32_bf16(af, bq[kc], sacc[jt], 0, 0, 0);
    }
  }
  __syncthreads();   // all waves done reading K; kp_lds becomes P

  float fac = 1.0f;
  if (ig < NT_) {
    const float* fp = F_part + ((size_t)bh*NT_ + ig)*12;
    float4 f0 = *(const float4*)fp;
    float4 f1 = *(const float4*)(fp+4);
    float4 f2 = *(const float4*)(fp+8);
    fac = box_b[h] + f0.x+f0.y+f0.z+f0.w + f1.x+f1.y+f1.z+f1.w + f2.x+f2.y+f2.z+f2.w;
  }
  const ushort* bT = biasTb + (size_t)h*NPAD_*NPAD_ + (size_t)(i0 + li)*NPAD_;  // i-major
  float mloc = -1e30f;
  #pragma unroll
  for (int jt = 0; jt < 16; ++jt) {
    us4 b4 = *(const us4*)(bT + jt*16 + g*4);
    #pragma unroll
    for (int r = 0; r < 4; ++r) {
      int j = jt*16 + g*4 + r;
      float sv = sacc[jt][r] + bf2f(b4[r]);
      if (ig < NT_ && j >= NT_) sv *= fac;
      if (j >= N_) sv = -1e30f;
      sacc[jt][r] = sv;
      mloc = fmaxf(mloc, sv);
    }
  }
  mloc = fmaxf(mloc, __shfl_xor(mloc, 16));
  mloc = fmaxf(mloc, __shfl_xor(mloc, 32));
  float ssum = 0.f;
  #pragma unroll
  for (int jt = 0; jt < 16; ++jt) {
    #pragma unroll
    for (int r = 0; r < 4; ++r) {
      float e = __expf(sacc[jt][r] - mloc);
      sacc[jt][r] = e;
      ssum += e;
    }
  }
  ssum += __shfl_xor(ssum, 16);
  ssum += __shfl_xor(ssum, 32);
  const float inv = 1.0f / ssum;

  ushort* pbase = kp_lds + wid*4096 + li*256;
  const int swz = (li & 7) << 3;
  #pragma unroll
  for (int jt = 0; jt < 16; ++jt) {
    unsigned w0 = (unsigned)f2bf(sacc[jt][0]*inv) | ((unsigned)f2bf(sacc[jt][1]*inv) << 16);
    unsigned w1 = (unsigned)f2bf(sacc[jt][2]*inv) | ((unsigned)f2bf(sacc[jt][3]*inv) << 16);
    *(uint2*)(pbase + ((jt*16 + g*4) ^ swz)) = make_uint2(w0, w1);
  }

  f32x4 oacc[4];
  #pragma unroll
  for (int dt = 0; dt < 4; ++dt) oacc[dt] = (f32x4){0.f,0.f,0.f,0.f};
  #pragma unroll
  for (int jc = 0; jc < 8; ++jc) {
    short8 pf = *(const short8*)(pbase + ((jc*32 + g*8) ^ swz));
    #pragma unroll
    for (int dt = 0; dt < 4; ++dt) {
      int row = dt*16 + li;
      short8 vf = *(const short8*)(Vb + row*NPAD_ + ((jc*32 + g*8) ^ ((row&7)<<3)));
      oacc[dt] = __builtin_amdgcn_mfma_f32_16x16x32_bf16(vf, pf, oacc[dt], 0, 0, 0);
    }
  }

  // ---- per-wave LDS transpose in own 8KB region (no barrier needed) ----
  float* tb = (float*)(kp_lds + wid*4096);
  #pragma unroll
  for (int dt = 0; dt < 4; ++dt)
    #pragma unroll
    for (int rr = 0; rr < 4; ++rr)
      tb[(dt*16 + g*4 + rr)*19 + li] = oacc[dt][rr];

  const int rtok = lane >> 2, cg = lane & 3;
  const int tokl = i0 + rtok;
  if (tokl < N_) {
    const int m = b*N_ + tokl;
    const int mbm = m >> 7, rr_ = m & 127, rx = rr_ & 7;
    const int kbb = h*2 + (cg >> 1);
    ushort* baseimg = attnimg + (((size_t)(mbm*KB_ + kbb))*128 + rr_)*64;
    #pragma unroll
    for (int half = 0; half < 2; ++half) {
      us8 hv, lv;
      #pragma unroll
      for (int e = 0; e < 8; ++e) {
        float v = tb[(cg*16 + half*8 + e)*19 + rtok];
        ushort hh, ll; split2(v, hh, ll);
        hv[e] = hh; lv[e] = ll;
      }
      const int c0 = (cg & 1)*2 + half;
      *(us8*)(baseimg + ((c0 ^ rx) * 8))        = hv;
      *(us8*)(baseimg + (((c0 ^ 4) ^ rx) * 8))  = lv;
    }
  }
}

extern "C" void kernel_launch(void* const* d_in, const int* in_sizes, int n_in,
                              void* d_out, int out_size, void* d_ws, size_t ws_size,
                              hipStream_t stream)
{
  const float* x         = (const float*)d_in[0];
  const float* boxmask   = (const float*)d_in[1];
  const float* qkv_w     = (const float*)d_in[2];
  const float* qkv_b     = (const float*)d_in[3];
  const float* proj_w    = (const float*)d_in[4];
  const float* proj_b    = (const float*)d_in[5];
  const float* box_w     = (const float*)d_in[6];
  const float* box_b     = (const float*)d_in[7];
  const float* rpe_table = (const float*)d_in[8];
  const int*   rpe_index = (const int*)d_in[9];
  const int rpe_m = in_sizes[8] / H_;   // 1698

  float* ws      = (float*)d_ws;
  float* G       = ws;                                   // 589,824 f
  float* F_part  = G + (size_t)B_*H_*H_*64;              // 451,584 f
  ushort* biasTb = (ushort*)(F_part + (size_t)B_*H_*NT_*12);  // 786,432 us
  ushort* ximg    = biasTb   + (size_t)H_*NPAD_*NPAD_;
  ushort* wqkvimg  = ximg     + (size_t)MP_*C_*2;        // 24,182,784 us
  ushort* wprojimg = wqkvimg  + (size_t)C3_*C_*2;        // 3,538,944 us
  ushort* Qimg     = wprojimg + (size_t)C_*C_*2;         // 1,179,648 us
  ushort* Kimg     = Qimg     + (size_t)B_*H_*NPAD_*64;  // 12,582,912 us each
  ushort* VTimg    = Kimg     + (size_t)B_*H_*NPAD_*64;
  ushort* attnimg  = ximg;   // alias: x image dead after QKV GEMM
  float* out     = (float*)d_out;

  // 0) merged prep: splits + bf16 biasT (i-major) + G
  prep_kernel<<<PREP_X_+PREP_WQ_+PREP_WP_+PREP_BT_+PREP_G_, 256, 0, stream>>>(
      x, qkv_w, proj_w, rpe_table, rpe_index, boxmask, box_w,
      ximg, wqkvimg, wprojimg, biasTb, G, rpe_m);
  // 1) QKV projection -> bf16 Q/K/VT images (XCD-swizzled 1D grid)
  gemm3_qkv_kernel<<<NWG_QKV_, 256, 0, stream>>>(wqkvimg, ximg, qkv_b, Qimg, Kimg, VTimg, KB_);
  // 2) template attention (MFMA) -> F_part
  tmpl_kernel<<<B_*H_, 256, 0, stream>>>(Qimg, Kimg, G, biasTb, F_part);
  // 3) MFMA attention -> attn image
  attn_mfma_kernel<<<B_*H_*4, 256, 0, stream>>>(Qimg, Kimg, VTimg, biasTb, F_part, box_b, attnimg);
  // 4) output projection (bf16x3 MFMA, fp32 out, XCD-swizzled)
  gemm3_kernel<<<NWG_PROJ_, 256, 0, stream>>>(attnimg, wprojimg, proj_b, out, KB_, C_, M_);
}

// Round 13
// 379.690 us; speedup vs baseline: 1.1716x; 1.1202x over previous
//
#include <hip/hip_runtime.h>
#include <hip/hip_bf16.h>

#define B_ 64
#define N_ 245
#define NT_ 49
#define H_ 12
#define HD_ 64
#define C_ 768
#define C3_ 2304
#define M_ (B_*N_)         // 15680 tokens
#define MP_ 15744          // padded to 123*128
#define MB_ 123
#define KB_ 24             // 768/32 k-blocks
#define SCALE_ 0.125f
#define NPAD_ 256
#define NWG_QKV_ (18*123)  // 2214
#define NWG_PROJ_ (6*123)  // 738

typedef short short8 __attribute__((ext_vector_type(8)));
typedef float f32x4 __attribute__((ext_vector_type(4)));
typedef ushort us8 __attribute__((ext_vector_type(8)));
typedef ushort us4 __attribute__((ext_vector_type(4)));
typedef _Float16 f16x8 __attribute__((ext_vector_type(8)));

__device__ __forceinline__ ushort f2bf(float f) {   // fp32 -> bf16 RTN
  unsigned u = __builtin_bit_cast(unsigned, f);
  u += 0x7fffu + ((u >> 16) & 1u);
  return (ushort)(u >> 16);
}
__device__ __forceinline__ float bf2f(ushort u) {
  return __builtin_bit_cast(float, ((unsigned)u) << 16);
}
// split a = hi + lo (both bf16; dropped error ~2^-16 relative)
__device__ __forceinline__ void split2(float a, ushort& hi, ushort& lo) {
  unsigned u = __builtin_bit_cast(unsigned, a);
  hi = (ushort)(u >> 16);
  float hf = __builtin_bit_cast(float, u & 0xffff0000u);
  lo = (ushort)(__builtin_bit_cast(unsigned, a - hf) >> 16);
}
// m204 bijective XCD swizzle
__device__ __forceinline__ int xcd_swz(int orig, int nwg) {
  const int q = nwg >> 3, r = nwg & 7;
  const int xcd = orig & 7, off = orig >> 3;
  return (xcd < r ? xcd*(q+1) : r*(q+1) + (xcd-r)*q) + off;
}

// ---- bf16x3 hi|lo image writer (proj path): [blk][row 128][hi 32 | lo 32] ----
__device__ __forceinline__ void split_dev(
    const float* __restrict__ A, ushort* __restrict__ img, int rows, int K, int idx)
{
  const int ch = idx & 3;
  const int r  = (idx >> 2) & 127;
  const int t  = idx >> 9;
  const int KBl = K >> 5;
  const int kb = t % KBl, mb = t / KBl;
  const int m = mb*128 + r;
  float4 v0 = make_float4(0,0,0,0), v1 = make_float4(0,0,0,0);
  if (m < rows) {
    const float* p = A + (size_t)m*K + kb*32 + ch*8;
    v0 = *(const float4*)p; v1 = *(const float4*)(p+4);
  }
  float vals[8] = {v0.x,v0.y,v0.z,v0.w,v1.x,v1.y,v1.z,v1.w};
  us8 hv, lv;
  #pragma unroll
  for (int e = 0; e < 8; ++e) { ushort hh, ll; split2(vals[e], hh, ll); hv[e]=hh; lv[e]=ll; }
  ushort* base = img + ((size_t)t*128 + r)*64;
  const int sw = (ch ^ (r&7))*8;
  *(us8*)(base + sw)        = hv;
  *(us8*)(base + (sw ^ 32)) = lv;
}

// ---- fp16 single image writer (QKV path): [blk][row 128][32 f16], chunk^(r&3) swz ----
__device__ __forceinline__ void splitf_dev(
    const float* __restrict__ A, ushort* __restrict__ img, int rows, int K, int idx)
{
  const int ch = idx & 3;
  const int r  = (idx >> 2) & 127;
  const int t  = idx >> 9;
  const int KBl = K >> 5;
  const int kb = t % KBl, mb = t / KBl;
  const int m = mb*128 + r;
  float4 v0 = make_float4(0,0,0,0), v1 = make_float4(0,0,0,0);
  if (m < rows) {
    const float* p = A + (size_t)m*K + kb*32 + ch*8;
    v0 = *(const float4*)p; v1 = *(const float4*)(p+4);
  }
  float vals[8] = {v0.x,v0.y,v0.z,v0.w,v1.x,v1.y,v1.z,v1.w};
  us8 hv;
  #pragma unroll
  for (int e = 0; e < 8; ++e) hv[e] = __builtin_bit_cast(ushort, (_Float16)vals[e]);
  ushort* base = img + ((size_t)t*128 + r)*32;
  *(us8*)(base + (ch ^ (r&3))*8) = hv;
}

// ---- merged prep ----
#define PREP_X_   5904   // 123*24*512/256
#define PREP_WQ_  864    // 18*24*512/256
#define PREP_WP_  288    // 6*24*512/256
#define PREP_BT_  2814   // ceil(12*245*245/256)
#define PREP_G_   768    // B_*H_
__global__ __launch_bounds__(256) void prep_kernel(
    const float* __restrict__ x, const float* __restrict__ qkv_w,
    const float* __restrict__ proj_w, const float* __restrict__ rpe_table,
    const int* __restrict__ rpe_index, const float* __restrict__ boxmask,
    const float* __restrict__ box_w,
    ushort* __restrict__ xfimg, ushort* __restrict__ wqfimg, ushort* __restrict__ wprojimg,
    ushort* __restrict__ biasTb, float* __restrict__ G, int rpe_m)
{
  __shared__ float bms[NT_][65];
  __shared__ float bws[H_][65];
  int id = blockIdx.x;
  const int tid = threadIdx.x;
  if (id < PREP_X_)  { splitf_dev(x,     xfimg,    M_,  C_, id*256 + tid); return; }
  id -= PREP_X_;
  if (id < PREP_WQ_) { splitf_dev(qkv_w, wqfimg,   C3_, C_, id*256 + tid); return; }
  id -= PREP_WQ_;
  if (id < PREP_WP_) { split_dev(proj_w, wprojimg, C_,  C_, id*256 + tid); return; }
  id -= PREP_WP_;
  if (id < PREP_BT_) {
    int idx = id*256 + tid;
    if (idx < H_*N_*N_) {
      int h = idx / (N_*N_);
      int rem = idx % (N_*N_);
      int i = rem / N_, j = rem % N_;   // j fastest: coalesced
      biasTb[((size_t)h*NPAD_ + i)*NPAD_ + j] = f2bf(rpe_table[h*rpe_m + rpe_index[i*N_ + j]]);
    }
    return;
  }
  id -= PREP_BT_;
  // G role: id = b*12 + ht
  {
    const int b = id / H_, ht = id % H_;
    for (int idx = tid; idx < NT_*64; idx += 256) {
      int j = idx >> 6, d = idx & 63;
      bms[j][d] = boxmask[((size_t)(b*NT_ + j))*C_ + ht*64 + d];
    }
    for (int idx = tid; idx < H_*64; idx += 256) {
      int h = idx >> 6, d = idx & 63;
      bws[h][d] = box_w[(size_t)h*C_ + ht*64 + d];
    }
    __syncthreads();
    for (int o = tid; o < H_*64; o += 256) {
      int h = o >> 6, j = o & 63;
      float s = 0.f;
      if (j < NT_) {
        #pragma unroll
        for (int d = 0; d < 64; ++d) s = fmaf(bws[h][d], bms[j][d], s);
      }
      G[(size_t)id*H_*64 + o] = s;
    }
  }
}

// ---- stage 16KB (bf16x3) / 8KB (fp16) tiles linearly into LDS ----
__device__ __forceinline__ void stage_tile(const ushort* __restrict__ src, ushort* dst,
                                           int wid, int lane) {
  #pragma unroll
  for (int t = 0; t < 4; ++t) {
    const int o = (wid*4 + t) * 512;
    __builtin_amdgcn_global_load_lds(
      (const __attribute__((address_space(1))) unsigned int*)(src + o + lane*8),
      (__attribute__((address_space(3))) unsigned int*)(dst + o),
      16, 0, 0);
  }
}
__device__ __forceinline__ void stage_tile8(const ushort* __restrict__ src, ushort* dst,
                                            int wid, int lane) {
  #pragma unroll
  for (int t = 0; t < 2; ++t) {
    const int o = (wid*2 + t) * 512;
    __builtin_amdgcn_global_load_lds(
      (const __attribute__((address_space(1))) unsigned int*)(src + o + lane*8),
      (__attribute__((address_space(3))) unsigned int*)(dst + o),
      16, 0, 0);
  }
}

// ---- bf16x3 GEMM (proj): Co = A @ B^T + bias, fp32 out ----
__global__ __launch_bounds__(256) void gemm3_kernel(
    const ushort* __restrict__ Aimg, const ushort* __restrict__ Bimg,
    const float* __restrict__ bias, float* __restrict__ Co,
    int KB, int Nn, int M)
{
  __shared__ __align__(16) ushort lds[2][16384];
  const int tid = threadIdx.x, lane = tid & 63, wid = tid >> 6;
  const int g = lane >> 4, li = lane & 15;
  const int sid = xcd_swz(blockIdx.x, NWG_PROJ_);
  const int nb = sid % 6, mb = sid / 6;
  const int wr = (wid >> 1) * 64, wc = (wid & 1) * 64;

  const ushort* Abase = Aimg + (size_t)mb * KB * 8192;
  const ushort* Bbase = Bimg + (size_t)nb * KB * 8192;

  f32x4 acc[4][4];
  #pragma unroll
  for (int i = 0; i < 4; ++i)
    #pragma unroll
    for (int j = 0; j < 4; ++j) acc[i][j] = (f32x4){0.f,0.f,0.f,0.f};

  stage_tile(Abase, &lds[0][0],    wid, lane);
  stage_tile(Bbase, &lds[0][8192], wid, lane);
  __syncthreads();

  for (int kb = 0; kb < KB; ++kb) {
    const int cur = kb & 1;
    if (kb + 1 < KB) {
      stage_tile(Abase + (size_t)(kb+1)*8192, &lds[cur^1][0],    wid, lane);
      stage_tile(Bbase + (size_t)(kb+1)*8192, &lds[cur^1][8192], wid, lane);
    }
    short8 ah[4], al[4], bh[4], bl[4];
    #pragma unroll
    for (int t = 0; t < 4; ++t) {
      const int ra = wr + t*16 + li;
      const ushort* Ar = &lds[cur][ra*64];
      const int ca = (g ^ (ra & 7)) * 8;
      ah[t] = *(const short8*)(Ar + ca);
      al[t] = *(const short8*)(Ar + (ca ^ 32));
      const int rb = wc + t*16 + li;
      const ushort* Br = &lds[cur][8192 + rb*64];
      const int cb = (g ^ (rb & 7)) * 8;
      bh[t] = *(const short8*)(Br + cb);
      bl[t] = *(const short8*)(Br + (cb ^ 32));
    }
    #pragma unroll
    for (int i = 0; i < 4; ++i)
      #pragma unroll
      for (int j = 0; j < 4; ++j) {
        acc[i][j] = __builtin_amdgcn_mfma_f32_16x16x32_bf16(ah[i], bh[j], acc[i][j], 0,0,0);
        acc[i][j] = __builtin_amdgcn_mfma_f32_16x16x32_bf16(al[i], bh[j], acc[i][j], 0,0,0);
        acc[i][j] = __builtin_amdgcn_mfma_f32_16x16x32_bf16(ah[i], bl[j], acc[i][j], 0,0,0);
      }
    __syncthreads();
  }

  #pragma unroll
  for (int i = 0; i < 4; ++i) {
    const int m0 = mb*128 + wr + i*16 + g*4;
    #pragma unroll
    for (int j = 0; j < 4; ++j) {
      const int n = nb*128 + wc + j*16 + li;
      const float bv = bias[n];
      #pragma unroll
      for (int rr = 0; rr < 4; ++rr) {
        const int m = m0 + rr;
        if (m < M) Co[(size_t)m * Nn + n] = acc[i][j][rr] + bv;
      }
    }
  }
}

// ---- fp16 single-MFMA QKV GEMM (W-major A): writes bf16 Q/K/VT images ----
__global__ __launch_bounds__(256) void gemm_f16_qkv_kernel(
    const ushort* __restrict__ Aimg, const ushort* __restrict__ Bimg,
    const float* __restrict__ bias,
    ushort* __restrict__ Qimg, ushort* __restrict__ Kimg, ushort* __restrict__ VTimg,
    int KB)
{
  __shared__ __align__(16) ushort lds[2][8192];   // [buf][A 4096 | B 4096]
  const int tid = threadIdx.x, lane = tid & 63, wid = tid >> 6;
  const int g = lane >> 4, li = lane & 15;
  const int sid = xcd_swz(blockIdx.x, NWG_QKV_);
  const int mb = sid % 18, nb = sid / 18;   // mb: channel block (fastest), nb: token block
  const int wr = (wid >> 1) * 64, wc = (wid & 1) * 64;

  const ushort* Abase = Aimg + (size_t)mb * KB * 4096;
  const ushort* Bbase = Bimg + (size_t)nb * KB * 4096;

  f32x4 acc[4][4];
  #pragma unroll
  for (int i = 0; i < 4; ++i)
    #pragma unroll
    for (int j = 0; j < 4; ++j) acc[i][j] = (f32x4){0.f,0.f,0.f,0.f};

  stage_tile8(Abase, &lds[0][0],    wid, lane);
  stage_tile8(Bbase, &lds[0][4096], wid, lane);
  __syncthreads();

  for (int kb = 0; kb < KB; ++kb) {
    const int cur = kb & 1;
    if (kb + 1 < KB) {
      stage_tile8(Abase + (size_t)(kb+1)*4096, &lds[cur^1][0],    wid, lane);
      stage_tile8(Bbase + (size_t)(kb+1)*4096, &lds[cur^1][4096], wid, lane);
    }
    f16x8 af[4], bf[4];
    #pragma unroll
    for (int t = 0; t < 4; ++t) {
      const int ra = wr + t*16 + li;
      af[t] = __builtin_bit_cast(f16x8,
          *(const short8*)(&lds[cur][ra*32 + ((g ^ (ra & 3)) * 8)]));
      const int rb = wc + t*16 + li;
      bf[t] = __builtin_bit_cast(f16x8,
          *(const short8*)(&lds[cur][4096 + rb*32 + ((g ^ (rb & 3)) * 8)]));
    }
    #pragma unroll
    for (int i = 0; i < 4; ++i)
      #pragma unroll
      for (int j = 0; j < 4; ++j)
        acc[i][j] = __builtin_amdgcn_mfma_f32_16x16x32_f16(af[i], bf[j], acc[i][j], 0,0,0);
    __syncthreads();
  }

  // epilogue: quad = channels ch0..ch0+3 at one token per (j,li)
  #pragma unroll
  for (int i = 0; i < 4; ++i) {
    const int ch0 = mb*128 + wr + i*16 + g*4;
    const int part = ch0 / 768;           // 0=q 1=k 2=v (uniform within quad/tile)
    const int rem  = ch0 - part*768;
    const int h = rem >> 6, d0 = rem & 63;
    const float b0 = bias[ch0+0], b1 = bias[ch0+1], b2 = bias[ch0+2], b3 = bias[ch0+3];
    #pragma unroll
    for (int j = 0; j < 4; ++j) {
      const int tok = nb*128 + wc + j*16 + li;
      if (tok < M_) {
        const int b = tok / 245;
        const int jl = tok - b*245;
        const int bh = b*H_ + h;
        if (part == 0) {
          us4 q4 = { f2bf((acc[i][j][0] + b0)*SCALE_), f2bf((acc[i][j][1] + b1)*SCALE_),
                     f2bf((acc[i][j][2] + b2)*SCALE_), f2bf((acc[i][j][3] + b3)*SCALE_) };
          *(us4*)(Qimg + ((size_t)bh*NPAD_ + jl)*64 + d0) = q4;
        } else if (part == 1) {
          us4 k4 = { f2bf(acc[i][j][0] + b0), f2bf(acc[i][j][1] + b1),
                     f2bf(acc[i][j][2] + b2), f2bf(acc[i][j][3] + b3) };
          *(us4*)(Kimg + ((size_t)bh*NPAD_ + jl)*64 + (d0 ^ ((jl&7)<<3))) = k4;
        } else {
          VTimg[((size_t)bh*64 + d0+0)*NPAD_ + (jl ^ (((d0+0)&7)<<3))] = f2bf(acc[i][j][0] + b0);
          VTimg[((size_t)bh*64 + d0+1)*NPAD_ + (jl ^ (((d0+1)&7)<<3))] = f2bf(acc[i][j][1] + b1);
          VTimg[((size_t)bh*64 + d0+2)*NPAD_ + (jl ^ (((d0+2)&7)<<3))] = f2bf(acc[i][j][2] + b2);
          VTimg[((size_t)bh*64 + d0+3)*NPAD_ + (jl ^ (((d0+3)&7)<<3))] = f2bf(acc[i][j][3] + b3);
        }
      }
    }
  }
}

// -------- template attention (MFMA) -> F_part[b,h,i,ht] = sum_j P[i,j]*G[b,ht,h,j] --------
__global__ __launch_bounds__(256) void tmpl_kernel(
    const ushort* __restrict__ Qimg, const ushort* __restrict__ Kimg,
    const float* __restrict__ G, const ushort* __restrict__ biasTb,
    float* __restrict__ F_part)
{
  __shared__ __align__(16) ushort kt_lds[64*64];   // first 64 K rows (swizzled image)
  __shared__ __align__(16) float Gs[H_*64];
  const int bx = blockIdx.x;       // b*12 + ht
  const int b = bx / H_, ht = bx % H_;
  const int tid = threadIdx.x, lane = tid & 63, wid = tid >> 6;
  const int g = lane >> 4, li = lane & 15;

  const ushort* Kb = Kimg + (size_t)bx*NPAD_*64;
  #pragma unroll
  for (int t = 0; t < 2; ++t) {
    const int o = (t*4 + wid) * 512;
    __builtin_amdgcn_global_load_lds(
      (const __attribute__((address_space(1))) unsigned int*)(Kb + o + lane*8),
      (__attribute__((address_space(3))) unsigned int*)(kt_lds + o), 16, 0, 0);
  }
  for (int idx = tid; idx < H_*64; idx += 256) Gs[idx] = G[(size_t)bx*H_*64 + idx];

  const int i = wid*16 + li;       // q-row 0..63 (template rows are 0..48)
  short8 bq[2];
  {
    const ushort* qp = Qimg + ((size_t)bx*NPAD_ + i)*64;   // Q pre-scaled
    bq[0] = *(const short8*)(qp + g*8);
    bq[1] = *(const short8*)(qp + 32 + g*8);
  }
  __syncthreads();

  f32x4 sacc[4];
  #pragma unroll
  for (int jt = 0; jt < 4; ++jt) sacc[jt] = (f32x4){0.f,0.f,0.f,0.f};
  #pragma unroll
  for (int jt = 0; jt < 4; ++jt) {
    int jr = jt*16 + li;
    #pragma unroll
    for (int kc = 0; kc < 2; ++kc) {
      short8 af = *(const short8*)(kt_lds + jr*64 + ((kc*32 + g*8) ^ ((jr&7)<<3)));
      sacc[jt] = __builtin_amdgcn_mfma_f32_16x16x32_bf16(af, bq[kc], sacc[jt], 0, 0, 0);
    }
  }

  const ushort* bT = biasTb + (size_t)ht*NPAD_*NPAD_ + (size_t)i*NPAD_;   // i-major
  float mloc = 0.f;                 // masked zeros join the max
  #pragma unroll
  for (int jt = 0; jt < 4; ++jt) {
    us4 b4 = *(const us4*)(bT + jt*16 + g*4);
    #pragma unroll
    for (int r = 0; r < 4; ++r) {
      int j = jt*16 + g*4 + r;
      float sv = (j < NT_) ? (sacc[jt][r] + bf2f(b4[r])) : -1e30f;
      sacc[jt][r] = sv;
      mloc = fmaxf(mloc, sv);
    }
  }
  mloc = fmaxf(mloc, __shfl_xor(mloc, 16));
  mloc = fmaxf(mloc, __shfl_xor(mloc, 32));
  float ssum = 0.f;
  #pragma unroll
  for (int jt = 0; jt < 4; ++jt)
    #pragma unroll
    for (int r = 0; r < 4; ++r) {
      int j = jt*16 + g*4 + r;
      float e = (j < NT_) ? __expf(sacc[jt][r] - mloc) : 0.f;
      sacc[jt][r] = e;
      ssum += e;
    }
  ssum += __shfl_xor(ssum, 16);
  ssum += __shfl_xor(ssum, 32);
  const float inv = 1.f / (ssum + 196.f * __expf(-mloc));   // 196 masked exp(0-mx)

  float F[12];
  #pragma unroll
  for (int h = 0; h < 12; ++h) F[h] = 0.f;
  #pragma unroll
  for (int jt = 0; jt < 4; ++jt) {
    f32x4 p = sacc[jt] * inv;
    #pragma unroll
    for (int h = 0; h < 12; ++h) {
      const float4 g4 = *(const float4*)(&Gs[h*64 + jt*16 + g*4]);
      F[h] = fmaf(p[0], g4.x, fmaf(p[1], g4.y, fmaf(p[2], g4.z, fmaf(p[3], g4.w, F[h]))));
    }
  }
  #pragma unroll
  for (int h = 0; h < 12; ++h) {
    F[h] += __shfl_xor(F[h], 16);
    F[h] += __shfl_xor(F[h], 32);
  }
  if (lane < 16 && i < NT_) {
    #pragma unroll
    for (int h = 0; h < 12; ++h)
      F_part[((size_t)(b*H_ + h)*NT_ + i)*12 + ht] = F[h];
  }
}

// -------- MFMA flash attention; V read direct from L2 (XOR-swizzled layout) --------
__global__ __launch_bounds__(256) void attn_mfma_kernel(
    const ushort* __restrict__ Qimg, const ushort* __restrict__ Kimg,
    const ushort* __restrict__ VTimg, const ushort* __restrict__ biasTb,
    const float* __restrict__ F_part, const float* __restrict__ box_b,
    ushort* __restrict__ attnimg)
{
  __shared__ __align__(16) ushort kp_lds[NPAD_*64];   // K image; then P; then O-transpose
  const int bx = blockIdx.x;
  const int bh = bx >> 2, rb = bx & 3;
  const int b = bh / H_, h = bh % H_;
  const int tid = threadIdx.x, lane = tid & 63, wid = tid >> 6;
  const int g = lane >> 4, li = lane & 15;

  const ushort* Kb = Kimg  + (size_t)bh*16384;
  const ushort* Vb = VTimg + (size_t)bh*16384;
  #pragma unroll
  for (int t = 0; t < 8; ++t) {
    const int o = (t*4 + wid) * 512;
    __builtin_amdgcn_global_load_lds(
      (const __attribute__((address_space(1))) unsigned int*)(Kb + o + lane*8),
      (__attribute__((address_space(3))) unsigned int*)(kp_lds + o), 16, 0, 0);
  }

  const int i0 = rb*64 + wid*16;
  const int ig = i0 + li;
  const int iq = (ig < N_) ? ig : (N_-1);
  short8 bq[2];
  {
    const ushort* qp = Qimg + ((size_t)bh*NPAD_ + iq)*64;   // Q pre-scaled
    bq[0] = *(const short8*)(qp + g*8);
    bq[1] = *(const short8*)(qp + 32 + g*8);
  }
  __syncthreads();

  f32x4 sacc[16];
  #pragma unroll
  for (int jt = 0; jt < 16; ++jt) sacc[jt] = (f32x4){0.f,0.f,0.f,0.f};
  #pragma unroll
  for (int jt = 0; jt < 16; ++jt) {
    int jr = jt*16 + li;
    #pragma unroll
    for (int kc = 0; kc < 2; ++kc) {
      short8 af = *(const short8*)(kp_lds + jr*64 + ((kc*32 + g*8) ^ ((jr&7)<<3)));
      sacc[jt] = __builtin_amdgcn_mfma_f32_16x16x32_bf16(af, bq[kc], sacc[jt], 0, 0, 0);
    }
  }
  __syncthreads();   // all waves done reading K; kp_lds becomes P

  float fac = 1.0f;
  if (ig < NT_) {
    const float* fp = F_part + ((size_t)bh*NT_ + ig)*12;
    float4 f0 = *(const float4*)fp;
    float4 f1 = *(const float4*)(fp+4);
    float4 f2 = *(const float4*)(fp+8);
    fac = box_b[h] + f0.x+f0.y+f0.z+f0.w + f1.x+f1.y+f1.z+f1.w + f2.x+f2.y+f2.z+f2.w;
  }
  const ushort* bT = biasTb + (size_t)h*NPAD_*NPAD_ + (size_t)(i0 + li)*NPAD_;  // i-major
  float mloc = -1e30f;
  #pragma unroll
  for (int jt = 0; jt < 16; ++jt) {
    us4 b4 = *(const us4*)(bT + jt*16 + g*4);
    #pragma unroll
    for (int r = 0; r < 4; ++r) {
      int j = jt*16 + g*4 + r;
      float sv = sacc[jt][r] + bf2f(b4[r]);
      if (ig < NT_ && j >= NT_) sv *= fac;
      if (j >= N_) sv = -1e30f;
      sacc[jt][r] = sv;
      mloc = fmaxf(mloc, sv);
    }
  }
  mloc = fmaxf(mloc, __shfl_xor(mloc, 16));
  mloc = fmaxf(mloc, __shfl_xor(mloc, 32));
  float ssum = 0.f;
  #pragma unroll
  for (int jt = 0; jt < 16; ++jt) {
    #pragma unroll
    for (int r = 0; r < 4; ++r) {
      float e = __expf(sacc[jt][r] - mloc);
      sacc[jt][r] = e;
      ssum += e;
    }
  }
  ssum += __shfl_xor(ssum, 16);
  ssum += __shfl_xor(ssum, 32);
  const float inv = 1.0f / ssum;

  ushort* pbase = kp_lds + wid*4096 + li*256;
  const int swz = (li & 7) << 3;
  #pragma unroll
  for (int jt = 0; jt < 16; ++jt) {
    unsigned w0 = (unsigned)f2bf(sacc[jt][0]*inv) | ((unsigned)f2bf(sacc[jt][1]*inv) << 16);
    unsigned w1 = (unsigned)f2bf(sacc[jt][2]*inv) | ((unsigned)f2bf(sacc[jt][3]*inv) << 16);
    *(uint2*)(pbase + ((jt*16 + g*4) ^ swz)) = make_uint2(w0, w1);
  }

  f32x4 oacc[4];
  #pragma unroll
  for (int dt = 0; dt < 4; ++dt) oacc[dt] = (f32x4){0.f,0.f,0.f,0.f};
  #pragma unroll
  for (int jc = 0; jc < 8; ++jc) {
    short8 pf = *(const short8*)(pbase + ((jc*32 + g*8) ^ swz));
    #pragma unroll
    for (int dt = 0; dt < 4; ++dt) {
      int row = dt*16 + li;
      short8 vf = *(const short8*)(Vb + row*NPAD_ + ((jc*32 + g*8) ^ ((row&7)<<3)));
      oacc[dt] = __builtin_amdgcn_mfma_f32_16x16x32_bf16(vf, pf, oacc[dt], 0, 0, 0);
    }
  }

  // ---- per-wave LDS transpose in own 8KB region (no barrier needed) ----
  float* tb = (float*)(kp_lds + wid*4096);
  #pragma unroll
  for (int dt = 0; dt < 4; ++dt)
    #pragma unroll
    for (int rr = 0; rr < 4; ++rr)
      tb[(dt*16 + g*4 + rr)*19 + li] = oacc[dt][rr];

  const int rtok = lane >> 2, cg = lane & 3;
  const int tokl = i0 + rtok;
  if (tokl < N_) {
    const int m = b*N_ + tokl;
    const int mbm = m >> 7, rr_ = m & 127, rx = rr_ & 7;
    const int kbb = h*2 + (cg >> 1);
    ushort* baseimg = attnimg + (((size_t)(mbm*KB_ + kbb))*128 + rr_)*64;
    #pragma unroll
    for (int half = 0; half < 2; ++half) {
      us8 hv, lv;
      #pragma unroll
      for (int e = 0; e < 8; ++e) {
        float v = tb[(cg*16 + half*8 + e)*19 + rtok];
        ushort hh, ll; split2(v, hh, ll);
        hv[e] = hh; lv[e] = ll;
      }
      const int c0 = (cg & 1)*2 + half;
      *(us8*)(baseimg + ((c0 ^ rx) * 8))        = hv;
      *(us8*)(baseimg + (((c0 ^ 4) ^ rx) * 8))  = lv;
    }
  }
}

extern "C" void kernel_launch(void* const* d_in, const int* in_sizes, int n_in,
                              void* d_out, int out_size, void* d_ws, size_t ws_size,
                              hipStream_t stream)
{
  const float* x         = (const float*)d_in[0];
  const float* boxmask   = (const float*)d_in[1];
  const float* qkv_w     = (const float*)d_in[2];
  const float* qkv_b     = (const float*)d_in[3];
  const float* proj_w    = (const float*)d_in[4];
  const float* proj_b    = (const float*)d_in[5];
  const float* box_w     = (const float*)d_in[6];
  const float* box_b     = (const float*)d_in[7];
  const float* rpe_table = (const float*)d_in[8];
  const int*   rpe_index = (const int*)d_in[9];
  const int rpe_m = in_sizes[8] / H_;   // 1698

  float* ws      = (float*)d_ws;
  float* G       = ws;                                      // 589,824 f
  float* F_part  = G + (size_t)B_*H_*H_*64;                 // 451,584 f
  ushort* biasTb = (ushort*)(F_part + (size_t)B_*H_*NT_*12);// 786,432 us
  ushort* xfimg    = biasTb   + (size_t)H_*NPAD_*NPAD_;     // 12,091,392 us (fp16)
  ushort* wqfimg   = xfimg    + (size_t)MB_*KB_*4096;       // 1,769,472 us (fp16)
  ushort* wprojimg = wqfimg   + (size_t)18*KB_*4096;        // 1,179,648 us (bf16x3)
  ushort* attnimg  = wprojimg + (size_t)C_*C_*2;            // 24,182,784 us (bf16x3)
  ushort* Qimg     = attnimg  + (size_t)MP_*C_*2;           // 12,582,912 us each
  ushort* Kimg     = Qimg     + (size_t)B_*H_*NPAD_*64;
  ushort* VTimg    = Kimg     + (size_t)B_*H_*NPAD_*64;
  float* out     = (float*)d_out;

  // 0) merged prep: fp16 x/qkv_w images + bf16x3 proj_w image + bf16 biasT + G
  prep_kernel<<<PREP_X_+PREP_WQ_+PREP_WP_+PREP_BT_+PREP_G_, 256, 0, stream>>>(
      x, qkv_w, proj_w, rpe_table, rpe_index, boxmask, box_w,
      xfimg, wqfimg, wprojimg, biasTb, G, rpe_m);
  // 1) QKV projection (fp16 single-MFMA) -> bf16 Q/K/VT images
  gemm_f16_qkv_kernel<<<NWG_QKV_, 256, 0, stream>>>(wqfimg, xfimg, qkv_b, Qimg, Kimg, VTimg, KB_);
  // 2) template attention (MFMA) -> F_part
  tmpl_kernel<<<B_*H_, 256, 0, stream>>>(Qimg, Kimg, G, biasTb, F_part);
  // 3) MFMA attention -> attn image
  attn_mfma_kernel<<<B_*H_*4, 256, 0, stream>>>(Qimg, Kimg, VTimg, biasTb, F_part, box_b, attnimg);
  // 4) output projection (bf16x3 MFMA, fp32 out, XCD-swizzled)
  gemm3_kernel<<<NWG_PROJ_, 256, 0, stream>>>(attnimg, wprojimg, proj_b, out, KB_, C_, M_);
}